// Round 8
// baseline (4912.257 us; speedup 1.0000x reference)
//
#include <hip/hip_runtime.h>
#include <stdint.h>

#define M_TOTAL 65536
#define IN_DIM 512
#define OBS_DIM 515

typedef __bf16 bf16x8 __attribute__((ext_vector_type(8)));
typedef float f32x4 __attribute__((ext_vector_type(4)));
typedef unsigned short u16x8 __attribute__((ext_vector_type(8)));

__device__ __forceinline__ unsigned short f2bf(float f) {
  unsigned u = __float_as_uint(f);
  u = (u + 0x7FFFu + ((u >> 16) & 1u)) >> 16;  // RNE
  return (unsigned short)u;
}
__device__ __forceinline__ float bf2f(unsigned short h) {
  return __uint_as_float(((unsigned)h) << 16);
}
__device__ __forceinline__ float fast_tanh(float z) {
  float e = __expf(2.0f * z);
  return 1.0f - 2.0f / (e + 1.0f);
}
__device__ __forceinline__ void gl16(const void* g, void* l) {
  __builtin_amdgcn_global_load_lds(
      (__attribute__((address_space(1))) void*)g,
      (__attribute__((address_space(3))) void*)l, 16, 0, 0);
}

// ---------------- fused weight cast (+ counter zeroing) ----------------
struct P8 { const float* p[8]; };

__global__ __launch_bounds__(256) void fused_cast(
    P8 srcs, unsigned short* __restrict__ dst, int* __restrict__ cnt) {
  if (blockIdx.x == 0 && threadIdx.x < 128) cnt[threadIdx.x] = 0;
  const int b0 = 524288, b1 = 1048576, b2 = 1572864, b3 = 2621440,
            b4 = 3670016, b5 = 4718592, b6 = 4849664, b7 = 4980736;
  int stride = gridDim.x * 256;
  for (int i = blockIdx.x * 256 + threadIdx.x; i < b7; i += stride) {
    const float* s; int off;
    if (i < b2)      { if (i < b0) { s = srcs.p[0]; off = i; }
                       else if (i < b1) { s = srcs.p[1]; off = i - b0; }
                       else { s = srcs.p[2]; off = i - b1; } }
    else if (i < b5) { if (i < b3) { s = srcs.p[3]; off = i - b2; }
                       else if (i < b4) { s = srcs.p[4]; off = i - b3; }
                       else { s = srcs.p[5]; off = i - b4; } }
    else             { if (i < b6) { s = srcs.p[6]; off = i - b5; }
                       else { s = srcs.p[7]; off = i - b6; } }
    dst[i] = f2bf(s[off]);
  }
}

// ---------------- compaction: hierarchical ----------------
__global__ __launch_bounds__(256) void compact_kernel(
    const float* __restrict__ obs,
    int* __restrict__ cntF, int* __restrict__ cntC,
    int* __restrict__ idxF, int* __restrict__ idxC, int C) {
  __shared__ int lcF, lcC, baseF, baseC;
  const int tid = threadIdx.x;
  const int r = blockIdx.x * 256 + tid;
  const float* g = obs + (size_t)r * OBS_DIM + IN_DIM;
  bool m = (fabsf(g[0]) <= 0.1f) && (fabsf(g[1]) <= 0.1f) && (fabsf(g[2]) <= 0.1f);
  if (tid == 0) { lcF = 0; lcC = 0; }
  __syncthreads();
  int slot = m ? atomicAdd(&lcF, 1) : atomicAdd(&lcC, 1);
  __syncthreads();
  const int c = r / C;
  if (tid == 0) {
    baseF = atomicAdd(&cntF[c], lcF);
    baseC = atomicAdd(&cntC[c], lcC);
  }
  __syncthreads();
  const int local = r - c * C;
  if (m) idxF[(size_t)c * C + baseF + slot] = local;
  else   idxC[(size_t)c * C + baseC + slot] = local;
}

// ---------------- padded permutation list (256-aligned groups) ----------------
__global__ __launch_bounds__(256) void build_idxP(
    const int* __restrict__ cntF, const int* __restrict__ cntC,
    const int* __restrict__ idxF, const int* __restrict__ idxC,
    int* __restrict__ idxP, int* __restrict__ meta, int C, int Cp) {
  const int bpc = Cp >> 8;
  const int c = blockIdx.x / bpc;
  const int i = (blockIdx.x % bpc) * 256 + threadIdx.x;
  const int cf = cntF[c], cc = cntC[c];
  const int padF = (cf + 255) & ~255;
  const int total = padF + ((cc + 255) & ~255);
  if ((blockIdx.x % bpc) == 0 && threadIdx.x == 0) {
    meta[2 * c] = padF; meta[2 * c + 1] = total;
  }
  if (i >= total) return;
  int v;
  if (i < padF) v = idxF[(size_t)c * C + (i < cf ? i : 0)];
  else { int j = i - padF; v = idxC[(size_t)c * C + (j < cc ? j : 0)]; }
  idxP[(size_t)c * Cp + i] = v;
}

__global__ __launch_bounds__(256) void prep_x(
    const float* __restrict__ obs, unsigned short* __restrict__ x, int row0) {
  int g = blockIdx.x * 256 + threadIdx.x;
  int row = g >> 9, col = g & 511;
  x[g] = f2bf(obs[(size_t)(row0 + row) * OBS_DIM + col]);
}

// ---------------- 256x256 GEMM, A via LDS dbuf + B direct from L2 --------------
// 512 threads (8 waves 2Mx4N), BK=64. LDS = 2 bufs x (A 256x64 bf16) = 64 KiB
// -> 2 blocks/CU. 4 phases/K-tile, 2 barriers; A-frag reads one phase ahead;
// B frags global->VGPR one phase ahead (L2-resident weights, never staged).
#define STAGE_A(h, tt, db) { \
    const unsigned short* _s = pA[h] + (size_t)(tt) * 64 + grp8; \
    char* _d = smem + (db) * 32768 + (h) * 16384 + wbase; \
    gl16(_s, _d); gl16(_s + 32, _d + 8192); }
#define RD_A(dst, base) \
  _Pragma("unroll") for (int _f = 0; _f < 4; ++_f) \
  _Pragma("unroll") for (int _k = 0; _k < 2; ++_k) \
    dst[_f][_k] = *(const bf16x8*)((base) + _k * 8192 + a_off[_f]);
#define LD_B0() { \
    bN0[0][0] = *(const bf16x8*)(pB0); bN0[0][1] = *(const bf16x8*)(pB0 + 32); \
    bN0[1][0] = *(const bf16x8*)(pB1); bN0[1][1] = *(const bf16x8*)(pB1 + 32); }
#define LD_B1() { \
    bN1[0][0] = *(const bf16x8*)(pB2); bN1[0][1] = *(const bf16x8*)(pB2 + 32); \
    bN1[1][0] = *(const bf16x8*)(pB3); bN1[1][1] = *(const bf16x8*)(pB3 + 32); }
#define MFMA16(AF, BFR, MB, NB) \
  _Pragma("unroll") for (int _f = 0; _f < 4; ++_f) \
  _Pragma("unroll") for (int _g = 0; _g < 2; ++_g) \
  _Pragma("unroll") for (int _k = 0; _k < 2; ++_k) \
    acc[(MB) + _f][(NB) + _g] = __builtin_amdgcn_mfma_f32_16x16x32_bf16( \
        AF[_f][_k], BFR[_g][_k], acc[(MB) + _f][(NB) + _g], 0, 0, 0);

__global__ __launch_bounds__(512, 4) void gemm256(
    const unsigned short* __restrict__ A, int lda,
    const unsigned short* __restrict__ BF, const unsigned short* __restrict__ BC,
    const float* __restrict__ biasF, const float* __restrict__ biasC,
    unsigned short* __restrict__ Cmat, int ldc, int K,
    const int* __restrict__ idxP, const int* __restrict__ meta, int Mrows)
{
  extern __shared__ char smem[];
  const int tid = threadIdx.x;

  // XCD-aware bijective swizzle (m204)
  const int nwg = gridDim.x * gridDim.y;
  const int orig = blockIdx.y * gridDim.x + blockIdx.x;
  const int qq = nwg >> 3, rr = nwg & 7, xc = orig & 7, oo = orig >> 3;
  const int wg = (xc < rr ? xc * (qq + 1) : rr * (qq + 1) + (xc - rr) * qq) + oo;
  const int n0 = (wg % gridDim.x) << 8;
  const int m0 = (wg / gridDim.x) << 8;

  const int padF  = meta ? meta[0] : (1 << 30);
  const int total = meta ? meta[1] : Mrows;
  if (m0 >= total) return;
  const unsigned short* B = (m0 < padF) ? BF : BC;
  const float* bias = (m0 < padF) ? biasF : biasC;

  const int lane = tid & 63;
  const int wv = tid >> 6;
  const int wm = wv >> 2, wn = wv & 3;
  const int lr = lane & 15;
  const int lk = lane >> 4;

  const int srow = tid >> 2;
  const int grp8 = (((tid & 3) ^ ((srow >> 1) & 3)) << 3);
  const int wbase = (tid & ~63) << 4;
  const unsigned short* pA[2];
#pragma unroll
  for (int h = 0; h < 2; ++h) {
    int gr = m0 + h * 128 + srow;
    int ga = idxP ? idxP[gr] : gr;
    pA[h] = A + (size_t)ga * lda;
  }

  int a_off[4];
#pragma unroll
  for (int f = 0; f < 4; ++f) {
    int hr = wm * 64 + f * 16 + lr;
    a_off[f] = hr * 64 + ((lk ^ ((hr >> 1) & 3)) << 4);
  }

  // B fragment pointers (direct global, L2-resident weights)
  const unsigned short* pB0 = B + (size_t)(n0 +       wn * 32 +      lr) * K + lk * 8;
  const unsigned short* pB1 = B + (size_t)(n0 +       wn * 32 + 16 + lr) * K + lk * 8;
  const unsigned short* pB2 = B + (size_t)(n0 + 128 + wn * 32 +      lr) * K + lk * 8;
  const unsigned short* pB3 = B + (size_t)(n0 + 128 + wn * 32 + 16 + lr) * K + lk * 8;

  const f32x4 zero = {0.f, 0.f, 0.f, 0.f};
  f32x4 acc[8][4];
#pragma unroll
  for (int i = 0; i < 8; ++i)
#pragma unroll
    for (int j = 0; j < 4; ++j) acc[i][j] = zero;

  const int NT = K >> 6;
  bf16x8 aA[4][2], aB[4][2], bN0[2][2], bN1[2][2];

  // prologue: stage A(0) both halves -> buf0, A0(1) -> buf1; load B(0) n-half0
  STAGE_A(0, 0, 0); STAGE_A(1, 0, 0); STAGE_A(0, 1, 1);
  LD_B0();
  asm volatile("s_waitcnt vmcnt(6)" ::: "memory");
  __builtin_amdgcn_s_barrier();
  __builtin_amdgcn_sched_barrier(0);
  RD_A(aA, smem);  // A0(0)

  for (int T = 0; T < NT; ++T) {
    const int b = T & 1;
    char* bufc = smem + (b << 15);
    char* bufn = smem + ((b ^ 1) << 15);
    const int tt1 = (T + 1 < NT) ? T + 1 : NT - 1;
    const int tt2 = (T + 2 < NT) ? T + 2 : NT - 1;

    // q0: load bN1(T); stage A1(tt1)->bufn; MFMA A0xB0; publish A1(T)
    LD_B1();
    STAGE_A(1, tt1, b ^ 1);
    __builtin_amdgcn_sched_barrier(0);
    __builtin_amdgcn_s_setprio(1);
    MFMA16(aA, bN0, 0, 0);
    __builtin_amdgcn_s_setprio(0);
    asm volatile("s_waitcnt vmcnt(8)" ::: "memory");
    __builtin_amdgcn_s_barrier();
    __builtin_amdgcn_sched_barrier(0);

    // q1: read A1(T) frags; MFMA A0xB1   (no barrier)
    RD_A(aB, bufc + 16384);
    __builtin_amdgcn_sched_barrier(0);
    __builtin_amdgcn_s_setprio(1);
    MFMA16(aA, bN1, 0, 2);
    __builtin_amdgcn_s_setprio(0);

    // q2: stage A0(tt2)->bufc; MFMA A1xB0; publish A0(T+1)
    STAGE_A(0, tt2, b);
    __builtin_amdgcn_sched_barrier(0);
    __builtin_amdgcn_s_setprio(1);
    MFMA16(aB, bN0, 4, 0);
    __builtin_amdgcn_s_setprio(0);
    asm volatile("s_waitcnt vmcnt(4)" ::: "memory");
    __builtin_amdgcn_s_barrier();
    __builtin_amdgcn_sched_barrier(0);

    // q3: read A0(T+1) frags; MFMA A1xB1; advance + load bN0(T+1)  (no barrier)
    RD_A(aA, bufn);
    __builtin_amdgcn_sched_barrier(0);
    __builtin_amdgcn_s_setprio(1);
    MFMA16(aB, bN1, 4, 2);
    __builtin_amdgcn_s_setprio(0);
    if (T + 1 < NT) { pB0 += 64; pB1 += 64; pB2 += 64; pB3 += 64; }
    LD_B0();
  }
  asm volatile("s_waitcnt vmcnt(0)" ::: "memory");

  // epilogue: bias + tanh + bf16 store
#pragma unroll
  for (int N = 0; N < 4; ++N) {
    const int nh = N >> 1, g = N & 1;
    int col = n0 + nh * 128 + wn * 32 + g * 16 + lr;
    float bv = bias[col];
#pragma unroll
    for (int M = 0; M < 8; ++M) {
      const int mh = M >> 2, f = M & 3;
      int rowb = m0 + mh * 128 + wm * 64 + f * 16 + lk * 4;
#pragma unroll
      for (int r = 0; r < 4; ++r)
        Cmat[(size_t)(rowb + r) * ldc + col] = f2bf(fast_tanh(acc[M][N][r] + bv));
    }
  }
}

// ---------------- layer3 policy ----------------
__global__ __launch_bounds__(256) void l3_policy_p(
    const unsigned short* __restrict__ H2,
    const unsigned short* __restrict__ W3F, const unsigned short* __restrict__ W3C,
    const float* __restrict__ b3F, const float* __restrict__ b3C,
    const int* __restrict__ idxP, const int* __restrict__ meta,
    float* __restrict__ out_pi, int row0)
{
  __shared__ alignas(16) unsigned short sA[128 * 32];
  __shared__ alignas(16) unsigned short sB[128 * 32];
  __shared__ int s_idx[128];
  const int tid = threadIdx.x;
  const int m0 = blockIdx.x << 7;
  const int padF = meta[0], total = meta[1];
  if (m0 >= total) return;
  const bool freeg = (m0 < padF);
  const unsigned short* W3 = freeg ? W3F : W3C;
  const float* b3 = freeg ? b3F : b3C;
  const int half = freeg ? 0 : 128;
  if (tid < 128) s_idx[tid] = idxP[m0 + tid];
  __syncthreads();

  const int lane = tid & 63;
  const int wv = tid >> 6;
  const int lr = lane & 15;
  const int lk = lane >> 4;

  const int ar0 = tid >> 2, ar1 = (256 + tid) >> 2;
  const int acol = (tid & 3) << 3;
  const unsigned short* Ap0 = H2 + (size_t)(m0 + ar0) * 1024 + acol;
  const unsigned short* Ap1 = H2 + (size_t)(m0 + ar1) * 1024 + acol;
  const unsigned short* Bp0 = W3 + (size_t)ar0 * 1024 + acol;
  const unsigned short* Bp1 = W3 + (size_t)ar1 * 1024 + acol;
  const int du = (tid & ~63) << 3;

  const f32x4 zero = {0.f, 0.f, 0.f, 0.f};
  f32x4 acc[2][8];
#pragma unroll
  for (int i = 0; i < 2; ++i)
#pragma unroll
    for (int j = 0; j < 8; ++j) acc[i][j] = zero;

  for (int kt = 0; kt < 1024; kt += 32) {
    __syncthreads();
    gl16(Ap0 + kt, &sA[du]);
    gl16(Bp0 + kt, &sB[du]);
    gl16(Ap1 + kt, &sA[du + 2048]);
    gl16(Bp1 + kt, &sB[du + 2048]);
    __syncthreads();
    bf16x8 af[2], bfr[8];
#pragma unroll
    for (int i = 0; i < 2; ++i)
      af[i] = *(const bf16x8*)&sA[((wv << 5) + (i << 4) + lr) * 32 + (lk << 3)];
#pragma unroll
    for (int j = 0; j < 8; ++j)
      bfr[j] = *(const bf16x8*)&sB[((j << 4) + lr) * 32 + (lk << 3)];
#pragma unroll
    for (int i = 0; i < 2; ++i)
#pragma unroll
      for (int j = 0; j < 8; ++j)
        acc[i][j] = __builtin_amdgcn_mfma_f32_16x16x32_bf16(af[i], bfr[j], acc[i][j], 0, 0, 0);
  }

  float bv[8];
#pragma unroll
  for (int j = 0; j < 8; ++j) bv[j] = b3[(j << 4) + lr];

#pragma unroll
  for (int i = 0; i < 2; ++i) {
#pragma unroll
    for (int r = 0; r < 4; ++r) {
      float lg[8];
      float mx = -3.4e38f;
#pragma unroll
      for (int j = 0; j < 8; ++j) { lg[j] = acc[i][j][r] + bv[j]; mx = fmaxf(mx, lg[j]); }
#pragma unroll
      for (int d = 1; d < 16; d <<= 1) mx = fmaxf(mx, __shfl_xor(mx, d));
      float s = 0.f;
#pragma unroll
      for (int j = 0; j < 8; ++j) { lg[j] = __expf(lg[j] - mx); s += lg[j]; }
#pragma unroll
      for (int d = 1; d < 16; d <<= 1) s += __shfl_xor(s, d);
      float inv = 1.f / s;
      int compact = m0 + (wv << 5) + (i << 4) + (lk << 2) + r;
      int grow = row0 + s_idx[compact - m0];
      size_t base = (size_t)grow * 256;
#pragma unroll
      for (int j = 0; j < 8; ++j)
        out_pi[base + half + (j << 4) + lr] = lg[j] * inv;
#pragma unroll
      for (int j = 0; j < 8; ++j)
        out_pi[base + (half ^ 128) + (j << 4) + lr] = 0.0f;
    }
  }
}

// ---------------- layer3 value ----------------
__global__ __launch_bounds__(256) void l3_value(
    const unsigned short* __restrict__ H2,
    const float* __restrict__ w3,
    const float* __restrict__ b3,
    float* __restrict__ out_v, int row0, int C)
{
  const int lane = threadIdx.x & 63;
  const int row = (blockIdx.x << 2) + (threadIdx.x >> 6);
  if (row >= C) return;
  float s = 0.f;
#pragma unroll
  for (int it = 0; it < 2; ++it) {
    int k = (it << 9) + (lane << 3);
    u16x8 h = *(const u16x8*)(H2 + (size_t)row * 1024 + k);
    const float4* wp = (const float4*)(w3 + k);
    float4 w0 = wp[0], w1 = wp[1];
    s += bf2f(h[0]) * w0.x + bf2f(h[1]) * w0.y + bf2f(h[2]) * w0.z + bf2f(h[3]) * w0.w;
    s += bf2f(h[4]) * w1.x + bf2f(h[5]) * w1.y + bf2f(h[6]) * w1.z + bf2f(h[7]) * w1.w;
  }
#pragma unroll
  for (int d = 1; d < 64; d <<= 1) s += __shfl_xor(s, d);
  if (lane == 0) out_v[row0 + row] = s + b3[0];
}

extern "C" void kernel_launch(void* const* d_in, const int* in_sizes, int n_in,
                              void* d_out, int out_size, void* d_ws, size_t ws_size,
                              hipStream_t stream)
{
  (void)in_sizes; (void)n_in; (void)out_size;
  const float* obs   = (const float*)d_in[0];
  const float* pf_w1 = (const float*)d_in[3];
  const float* pf_b1 = (const float*)d_in[4];
  const float* pf_w2 = (const float*)d_in[5];
  const float* pf_b2 = (const float*)d_in[6];
  const float* pf_w3 = (const float*)d_in[7];
  const float* pf_b3 = (const float*)d_in[8];
  const float* pc_w1 = (const float*)d_in[9];
  const float* pc_b1 = (const float*)d_in[10];
  const float* pc_w2 = (const float*)d_in[11];
  const float* pc_b2 = (const float*)d_in[12];
  const float* pc_w3 = (const float*)d_in[13];
  const float* pc_b3 = (const float*)d_in[14];
  const float* v_w1  = (const float*)d_in[15];
  const float* v_b1  = (const float*)d_in[16];
  const float* v_w2  = (const float*)d_in[17];
  const float* v_b2  = (const float*)d_in[18];
  const float* v_w3  = (const float*)d_in[19];
  const float* v_b3  = (const float*)d_in[20];

  float* out_pi = (float*)d_out;
  float* out_v  = out_pi + (size_t)M_TOTAL * 256;

  char* ws = (char*)d_ws;
  unsigned short* wPF1 = (unsigned short*)ws;
  unsigned short* wPC1 = wPF1 + 524288;
  unsigned short* wV1  = wPC1 + 524288;
  unsigned short* wPF2 = wV1  + 524288;
  unsigned short* wPC2 = wPF2 + 1048576;
  unsigned short* wV2  = wPC2 + 1048576;
  unsigned short* wPF3 = wV2  + 1048576;
  unsigned short* wPC3 = wPF3 + 131072;
  int* cntF = (int*)(wPC3 + 131072);
  int* cntC = cntF + 64;
  int* idxF = cntC + 64;
  int* idxC = idxF + 65536;
  int* meta = idxC + 65536;
  int* idxP = meta + 128;                  // up to 81920 ints
  unsigned short* xb = (unsigned short*)(idxP + 81920);

  const size_t fixed = (size_t)9961472 + 4 * (64 + 64 + 65536 + 65536 + 128 + 81920);
  int C = 1024;
  if      (ws_size >= fixed + 5120ull * 65536 + 3145728) C = 65536;
  else if (ws_size >= fixed + 5120ull * 32768 + 3145728) C = 32768;
  else if (ws_size >= fixed + 5120ull * 16384 + 3145728) C = 16384;
  else if (ws_size >= fixed + 5120ull *  8192 + 3145728) C = 8192;
  else if (ws_size >= fixed + 5120ull *  4096 + 3145728) C = 4096;
  else if (ws_size >= fixed + 5120ull *  2048 + 3145728) C = 2048;
  const int nchunk = M_TOTAL / C;
  const int Cp = C + 512;

  unsigned short* h1p = xb + (size_t)C * 512;
  unsigned short* h2p = h1p + (size_t)Cp * 1024;

  (void)hipFuncSetAttribute((const void*)gemm256,
      hipFuncAttributeMaxDynamicSharedMemorySize, 65536);

  P8 srcs;
  srcs.p[0] = pf_w1; srcs.p[1] = pc_w1; srcs.p[2] = v_w1;
  srcs.p[3] = pf_w2; srcs.p[4] = pc_w2; srcs.p[5] = v_w2;
  srcs.p[6] = pf_w3; srcs.p[7] = pc_w3;
  fused_cast<<<2048, 256, 0, stream>>>(srcs, wPF1, cntF);
  compact_kernel<<<M_TOTAL / 256, 256, 0, stream>>>(obs, cntF, cntC, idxF, idxC, C);
  build_idxP<<<nchunk * (Cp / 256), 256, 0, stream>>>(cntF, cntC, idxF, idxC, idxP, meta, C, Cp);

  const dim3 gv(4, C / 256);
  const dim3 gp(4, Cp / 256);
  for (int c = 0; c < nchunk; ++c) {
    int row0 = c * C;
    prep_x<<<C * 512 / 256, 256, 0, stream>>>(obs, xb, row0);
    // value MLP (all rows, identity)
    gemm256<<<gv, 512, 65536, stream>>>(xb, 512, wV1, wV1, v_b1, v_b1,
                                        h1p, 1024, 512, nullptr, nullptr, C);
    gemm256<<<gv, 512, 65536, stream>>>(h1p, 1024, wV2, wV2, v_b2, v_b2,
                                        h2p, 1024, 1024, nullptr, nullptr, C);
    l3_value<<<C / 4, 256, 0, stream>>>(h2p, v_w3, v_b3, out_v, row0, C);
    // policy MLP (padded permutation: free tiles then con tiles)
    gemm256<<<gp, 512, 65536, stream>>>(xb, 512, wPF1, wPC1, pf_b1, pc_b1,
                                        h1p, 1024, 512, idxP + (size_t)c * Cp, meta + 2 * c, 0);
    gemm256<<<gp, 512, 65536, stream>>>(h1p, 1024, wPF2, wPC2, pf_b2, pc_b2,
                                        h2p, 1024, 1024, nullptr, meta + 2 * c, 0);
    l3_policy_p<<<Cp / 128, 256, 0, stream>>>(h2p, wPF3, wPC3, pf_b3, pc_b3,
                                              idxP + (size_t)c * Cp, meta + 2 * c, out_pi, row0);
  }
}

// Round 10
// 1020.605 us; speedup vs baseline: 4.8131x; 4.8131x over previous
//
#include <hip/hip_runtime.h>
#include <stdint.h>

#define M_TOTAL 65536
#define IN_DIM 512
#define OBS_DIM 515

typedef __bf16 bf16x8 __attribute__((ext_vector_type(8)));
typedef float f32x4 __attribute__((ext_vector_type(4)));
typedef unsigned short u16x8 __attribute__((ext_vector_type(8)));

__device__ __forceinline__ unsigned short f2bf(float f) {
  unsigned u = __float_as_uint(f);
  u = (u + 0x7FFFu + ((u >> 16) & 1u)) >> 16;  // RNE
  return (unsigned short)u;
}
__device__ __forceinline__ float bf2f(unsigned short h) {
  return __uint_as_float(((unsigned)h) << 16);
}
__device__ __forceinline__ float fast_tanh(float z) {
  float e = __expf(2.0f * z);
  return 1.0f - 2.0f / (e + 1.0f);
}
__device__ __forceinline__ void gl16(const void* g, void* l) {
  __builtin_amdgcn_global_load_lds(
      (__attribute__((address_space(1))) void*)g,
      (__attribute__((address_space(3))) void*)l, 16, 0, 0);
}

// ---------------- fused weight cast (+ counter zeroing) ----------------
struct P8 { const float* p[8]; };

__global__ __launch_bounds__(256) void fused_cast(
    P8 srcs, unsigned short* __restrict__ dst, int* __restrict__ cnt) {
  if (blockIdx.x == 0 && threadIdx.x < 128) cnt[threadIdx.x] = 0;
  const int b0 = 524288, b1 = 1048576, b2 = 1572864, b3 = 2621440,
            b4 = 3670016, b5 = 4718592, b6 = 4849664, b7 = 4980736;
  int stride = gridDim.x * 256;
  for (int i = blockIdx.x * 256 + threadIdx.x; i < b7; i += stride) {
    const float* s; int off;
    if (i < b2)      { if (i < b0) { s = srcs.p[0]; off = i; }
                       else if (i < b1) { s = srcs.p[1]; off = i - b0; }
                       else { s = srcs.p[2]; off = i - b1; } }
    else if (i < b5) { if (i < b3) { s = srcs.p[3]; off = i - b2; }
                       else if (i < b4) { s = srcs.p[4]; off = i - b3; }
                       else { s = srcs.p[5]; off = i - b4; } }
    else             { if (i < b6) { s = srcs.p[6]; off = i - b5; }
                       else { s = srcs.p[7]; off = i - b6; } }
    dst[i] = f2bf(s[off]);
  }
}

// ---------------- compaction: hierarchical ----------------
__global__ __launch_bounds__(256) void compact_kernel(
    const float* __restrict__ obs,
    int* __restrict__ cntF, int* __restrict__ cntC,
    int* __restrict__ idxF, int* __restrict__ idxC, int C) {
  __shared__ int lcF, lcC, baseF, baseC;
  const int tid = threadIdx.x;
  const int r = blockIdx.x * 256 + tid;
  const float* g = obs + (size_t)r * OBS_DIM + IN_DIM;
  bool m = (fabsf(g[0]) <= 0.1f) && (fabsf(g[1]) <= 0.1f) && (fabsf(g[2]) <= 0.1f);
  if (tid == 0) { lcF = 0; lcC = 0; }
  __syncthreads();
  int slot = m ? atomicAdd(&lcF, 1) : atomicAdd(&lcC, 1);
  __syncthreads();
  const int c = r / C;
  if (tid == 0) {
    baseF = atomicAdd(&cntF[c], lcF);
    baseC = atomicAdd(&cntC[c], lcC);
  }
  __syncthreads();
  const int local = r - c * C;
  if (m) idxF[(size_t)c * C + baseF + slot] = local;
  else   idxC[(size_t)c * C + baseC + slot] = local;
}

// ---------------- padded permutation list (256-aligned groups) ----------------
__global__ __launch_bounds__(256) void build_idxP(
    const int* __restrict__ cntF, const int* __restrict__ cntC,
    const int* __restrict__ idxF, const int* __restrict__ idxC,
    int* __restrict__ idxP, int* __restrict__ meta, int C, int Cp) {
  const int bpc = Cp >> 8;
  const int c = blockIdx.x / bpc;
  const int i = (blockIdx.x % bpc) * 256 + threadIdx.x;
  const int cf = cntF[c], cc = cntC[c];
  const int padF = (cf + 255) & ~255;
  const int total = padF + ((cc + 255) & ~255);
  if ((blockIdx.x % bpc) == 0 && threadIdx.x == 0) {
    meta[2 * c] = padF; meta[2 * c + 1] = total;
  }
  if (i >= total) return;
  int v;
  if (i < padF) v = idxF[(size_t)c * C + (i < cf ? i : 0)];
  else { int j = i - padF; v = idxC[(size_t)c * C + (j < cc ? j : 0)]; }
  idxP[(size_t)c * Cp + i] = v;
}

__global__ __launch_bounds__(256) void prep_x(
    const float* __restrict__ obs, unsigned short* __restrict__ x, int row0) {
  int g = blockIdx.x * 256 + threadIdx.x;
  int row = g >> 9, col = g & 511;
  x[g] = f2bf(obs[(size_t)(row0 + row) * OBS_DIM + col]);
}

// ---------------- 256x256 GEMM, A via LDS dbuf + B direct from L2 --------------
// 512 threads (8 waves 2Mx4N), BK=64. LDS = 2 bufs x (A 256x64 bf16) = 64 KiB.
// __launch_bounds__(512,2): 256-VGPR budget -- (512,4) spilled the accumulator
// (round 8: 6.5 GB/dispatch scratch traffic). PROLOGUE uses vmcnt(0): plain B
// loads may be compiler-reordered before the gl16s, so a counted vmcnt there
// published unlanded LDS (round 9 race). Steady-state counted vmcnts verified
// robust to arbitrary intra-cluster issue order.
#define STAGE_A(h, tt, db) { \
    const unsigned short* _s = pA[h] + (size_t)(tt) * 64 + grp8; \
    char* _d = smem + (db) * 32768 + (h) * 16384 + wbase; \
    gl16(_s, _d); gl16(_s + 32, _d + 8192); }
#define RD_A(dst, base) \
  _Pragma("unroll") for (int _f = 0; _f < 4; ++_f) \
  _Pragma("unroll") for (int _k = 0; _k < 2; ++_k) \
    dst[_f][_k] = *(const bf16x8*)((base) + _k * 8192 + a_off[_f]);
#define LD_B0() { \
    bN0[0][0] = *(const bf16x8*)(pB0); bN0[0][1] = *(const bf16x8*)(pB0 + 32); \
    bN0[1][0] = *(const bf16x8*)(pB1); bN0[1][1] = *(const bf16x8*)(pB1 + 32); }
#define LD_B1() { \
    bN1[0][0] = *(const bf16x8*)(pB2); bN1[0][1] = *(const bf16x8*)(pB2 + 32); \
    bN1[1][0] = *(const bf16x8*)(pB3); bN1[1][1] = *(const bf16x8*)(pB3 + 32); }
#define MFMA16(AF, BFR, MB, NB) \
  _Pragma("unroll") for (int _f = 0; _f < 4; ++_f) \
  _Pragma("unroll") for (int _g = 0; _g < 2; ++_g) \
  _Pragma("unroll") for (int _k = 0; _k < 2; ++_k) \
    acc[(MB) + _f][(NB) + _g] = __builtin_amdgcn_mfma_f32_16x16x32_bf16( \
        AF[_f][_k], BFR[_g][_k], acc[(MB) + _f][(NB) + _g], 0, 0, 0);

__global__ __launch_bounds__(512, 2) void gemm256(
    const unsigned short* __restrict__ A, int lda,
    const unsigned short* __restrict__ BF, const unsigned short* __restrict__ BC,
    const float* __restrict__ biasF, const float* __restrict__ biasC,
    unsigned short* __restrict__ Cmat, int ldc, int K,
    const int* __restrict__ idxP, const int* __restrict__ meta, int Mrows)
{
  extern __shared__ char smem[];
  const int tid = threadIdx.x;

  // XCD-aware bijective swizzle (m204)
  const int nwg = gridDim.x * gridDim.y;
  const int orig = blockIdx.y * gridDim.x + blockIdx.x;
  const int qq = nwg >> 3, rr = nwg & 7, xc = orig & 7, oo = orig >> 3;
  const int wg = (xc < rr ? xc * (qq + 1) : rr * (qq + 1) + (xc - rr) * qq) + oo;
  const int n0 = (wg % gridDim.x) << 8;
  const int m0 = (wg / gridDim.x) << 8;

  const int padF  = meta ? meta[0] : (1 << 30);
  const int total = meta ? meta[1] : Mrows;
  if (m0 >= total) return;
  const unsigned short* B = (m0 < padF) ? BF : BC;
  const float* bias = (m0 < padF) ? biasF : biasC;

  const int lane = tid & 63;
  const int wv = tid >> 6;
  const int wm = wv >> 2, wn = wv & 3;
  const int lr = lane & 15;
  const int lk = lane >> 4;

  const int srow = tid >> 2;
  const int grp8 = (((tid & 3) ^ ((srow >> 1) & 3)) << 3);
  const int wbase = (tid & ~63) << 4;
  const unsigned short* pA[2];
#pragma unroll
  for (int h = 0; h < 2; ++h) {
    int gr = m0 + h * 128 + srow;
    int ga = idxP ? idxP[gr] : gr;
    pA[h] = A + (size_t)ga * lda;
  }

  int a_off[4];
#pragma unroll
  for (int f = 0; f < 4; ++f) {
    int hr = wm * 64 + f * 16 + lr;
    a_off[f] = hr * 64 + ((lk ^ ((hr >> 1) & 3)) << 4);
  }

  // B fragment pointers (direct global, L2-resident weights)
  const unsigned short* pB0 = B + (size_t)(n0 +       wn * 32 +      lr) * K + lk * 8;
  const unsigned short* pB1 = B + (size_t)(n0 +       wn * 32 + 16 + lr) * K + lk * 8;
  const unsigned short* pB2 = B + (size_t)(n0 + 128 + wn * 32 +      lr) * K + lk * 8;
  const unsigned short* pB3 = B + (size_t)(n0 + 128 + wn * 32 + 16 + lr) * K + lk * 8;

  const f32x4 zero = {0.f, 0.f, 0.f, 0.f};
  f32x4 acc[8][4];
#pragma unroll
  for (int i = 0; i < 8; ++i)
#pragma unroll
    for (int j = 0; j < 4; ++j) acc[i][j] = zero;

  const int NT = K >> 6;
  bf16x8 aA[4][2], aB[4][2], bN0[2][2], bN1[2][2];

  // prologue: stage A(0) both halves -> buf0, A0(1) -> buf1; load B(0) n-half0
  // FULL drain: plain loads/gl16 issue order is compiler-chosen, so a counted
  // vmcnt here can publish unlanded LDS (round-9 race). Runs once; ~free.
  STAGE_A(0, 0, 0); STAGE_A(1, 0, 0); STAGE_A(0, 1, 1);
  LD_B0();
  asm volatile("s_waitcnt vmcnt(0)" ::: "memory");
  __builtin_amdgcn_s_barrier();
  __builtin_amdgcn_sched_barrier(0);
  RD_A(aA, smem);  // A0(0)

  for (int T = 0; T < NT; ++T) {
    const int b = T & 1;
    char* bufc = smem + (b << 15);
    char* bufn = smem + ((b ^ 1) << 15);
    const int tt1 = (T + 1 < NT) ? T + 1 : NT - 1;
    const int tt2 = (T + 2 < NT) ? T + 2 : NT - 1;

    // q0: load bN1(T); stage A1(tt1)->bufn; MFMA A0xB0; publish A1(T)
    LD_B1();
    STAGE_A(1, tt1, b ^ 1);
    __builtin_amdgcn_sched_barrier(0);
    __builtin_amdgcn_s_setprio(1);
    MFMA16(aA, bN0, 0, 0);
    __builtin_amdgcn_s_setprio(0);
    asm volatile("s_waitcnt vmcnt(8)" ::: "memory");
    __builtin_amdgcn_s_barrier();
    __builtin_amdgcn_sched_barrier(0);

    // q1: read A1(T) frags; MFMA A0xB1   (no barrier)
    RD_A(aB, bufc + 16384);
    __builtin_amdgcn_sched_barrier(0);
    __builtin_amdgcn_s_setprio(1);
    MFMA16(aA, bN1, 0, 2);
    __builtin_amdgcn_s_setprio(0);

    // q2: stage A0(tt2)->bufc; MFMA A1xB0; publish A0(T+1)
    STAGE_A(0, tt2, b);
    __builtin_amdgcn_sched_barrier(0);
    __builtin_amdgcn_s_setprio(1);
    MFMA16(aB, bN0, 4, 0);
    __builtin_amdgcn_s_setprio(0);
    asm volatile("s_waitcnt vmcnt(4)" ::: "memory");
    __builtin_amdgcn_s_barrier();
    __builtin_amdgcn_sched_barrier(0);

    // q3: read A0(T+1) frags; MFMA A1xB1; advance + load bN0(T+1)  (no barrier)
    RD_A(aA, bufn);
    __builtin_amdgcn_sched_barrier(0);
    __builtin_amdgcn_s_setprio(1);
    MFMA16(aB, bN1, 4, 2);
    __builtin_amdgcn_s_setprio(0);
    if (T + 1 < NT) { pB0 += 64; pB1 += 64; pB2 += 64; pB3 += 64; }
    LD_B0();
  }
  asm volatile("s_waitcnt vmcnt(0)" ::: "memory");

  // epilogue: bias + tanh + bf16 store
#pragma unroll
  for (int N = 0; N < 4; ++N) {
    const int nh = N >> 1, g = N & 1;
    int col = n0 + nh * 128 + wn * 32 + g * 16 + lr;
    float bv = bias[col];
#pragma unroll
    for (int M = 0; M < 8; ++M) {
      const int mh = M >> 2, f = M & 3;
      int rowb = m0 + mh * 128 + wm * 64 + f * 16 + lk * 4;
#pragma unroll
      for (int r = 0; r < 4; ++r)
        Cmat[(size_t)(rowb + r) * ldc + col] = f2bf(fast_tanh(acc[M][N][r] + bv));
    }
  }
}

// ---------------- layer3 policy ----------------
__global__ __launch_bounds__(256) void l3_policy_p(
    const unsigned short* __restrict__ H2,
    const unsigned short* __restrict__ W3F, const unsigned short* __restrict__ W3C,
    const float* __restrict__ b3F, const float* __restrict__ b3C,
    const int* __restrict__ idxP, const int* __restrict__ meta,
    float* __restrict__ out_pi, int row0)
{
  __shared__ alignas(16) unsigned short sA[128 * 32];
  __shared__ alignas(16) unsigned short sB[128 * 32];
  __shared__ int s_idx[128];
  const int tid = threadIdx.x;
  const int m0 = blockIdx.x << 7;
  const int padF = meta[0], total = meta[1];
  if (m0 >= total) return;
  const bool freeg = (m0 < padF);
  const unsigned short* W3 = freeg ? W3F : W3C;
  const float* b3 = freeg ? b3F : b3C;
  const int half = freeg ? 0 : 128;
  if (tid < 128) s_idx[tid] = idxP[m0 + tid];
  __syncthreads();

  const int lane = tid & 63;
  const int wv = tid >> 6;
  const int lr = lane & 15;
  const int lk = lane >> 4;

  const int ar0 = tid >> 2, ar1 = (256 + tid) >> 2;
  const int acol = (tid & 3) << 3;
  const unsigned short* Ap0 = H2 + (size_t)(m0 + ar0) * 1024 + acol;
  const unsigned short* Ap1 = H2 + (size_t)(m0 + ar1) * 1024 + acol;
  const unsigned short* Bp0 = W3 + (size_t)ar0 * 1024 + acol;
  const unsigned short* Bp1 = W3 + (size_t)ar1 * 1024 + acol;
  const int du = (tid & ~63) << 3;

  const f32x4 zero = {0.f, 0.f, 0.f, 0.f};
  f32x4 acc[2][8];
#pragma unroll
  for (int i = 0; i < 2; ++i)
#pragma unroll
    for (int j = 0; j < 8; ++j) acc[i][j] = zero;

  for (int kt = 0; kt < 1024; kt += 32) {
    __syncthreads();
    gl16(Ap0 + kt, &sA[du]);
    gl16(Bp0 + kt, &sB[du]);
    gl16(Ap1 + kt, &sA[du + 2048]);
    gl16(Bp1 + kt, &sB[du + 2048]);
    __syncthreads();
    bf16x8 af[2], bfr[8];
#pragma unroll
    for (int i = 0; i < 2; ++i)
      af[i] = *(const bf16x8*)&sA[((wv << 5) + (i << 4) + lr) * 32 + (lk << 3)];
#pragma unroll
    for (int j = 0; j < 8; ++j)
      bfr[j] = *(const bf16x8*)&sB[((j << 4) + lr) * 32 + (lk << 3)];
#pragma unroll
    for (int i = 0; i < 2; ++i)
#pragma unroll
      for (int j = 0; j < 8; ++j)
        acc[i][j] = __builtin_amdgcn_mfma_f32_16x16x32_bf16(af[i], bfr[j], acc[i][j], 0, 0, 0);
  }

  float bv[8];
#pragma unroll
  for (int j = 0; j < 8; ++j) bv[j] = b3[(j << 4) + lr];

#pragma unroll
  for (int i = 0; i < 2; ++i) {
#pragma unroll
    for (int r = 0; r < 4; ++r) {
      float lg[8];
      float mx = -3.4e38f;
#pragma unroll
      for (int j = 0; j < 8; ++j) { lg[j] = acc[i][j][r] + bv[j]; mx = fmaxf(mx, lg[j]); }
#pragma unroll
      for (int d = 1; d < 16; d <<= 1) mx = fmaxf(mx, __shfl_xor(mx, d));
      float s = 0.f;
#pragma unroll
      for (int j = 0; j < 8; ++j) { lg[j] = __expf(lg[j] - mx); s += lg[j]; }
#pragma unroll
      for (int d = 1; d < 16; d <<= 1) s += __shfl_xor(s, d);
      float inv = 1.f / s;
      int compact = m0 + (wv << 5) + (i << 4) + (lk << 2) + r;
      int grow = row0 + s_idx[compact - m0];
      size_t base = (size_t)grow * 256;
#pragma unroll
      for (int j = 0; j < 8; ++j)
        out_pi[base + half + (j << 4) + lr] = lg[j] * inv;
#pragma unroll
      for (int j = 0; j < 8; ++j)
        out_pi[base + (half ^ 128) + (j << 4) + lr] = 0.0f;
    }
  }
}

// ---------------- layer3 value ----------------
__global__ __launch_bounds__(256) void l3_value(
    const unsigned short* __restrict__ H2,
    const float* __restrict__ w3,
    const float* __restrict__ b3,
    float* __restrict__ out_v, int row0, int C)
{
  const int lane = threadIdx.x & 63;
  const int row = (blockIdx.x << 2) + (threadIdx.x >> 6);
  if (row >= C) return;
  float s = 0.f;
#pragma unroll
  for (int it = 0; it < 2; ++it) {
    int k = (it << 9) + (lane << 3);
    u16x8 h = *(const u16x8*)(H2 + (size_t)row * 1024 + k);
    const float4* wp = (const float4*)(w3 + k);
    float4 w0 = wp[0], w1 = wp[1];
    s += bf2f(h[0]) * w0.x + bf2f(h[1]) * w0.y + bf2f(h[2]) * w0.z + bf2f(h[3]) * w0.w;
    s += bf2f(h[4]) * w1.x + bf2f(h[5]) * w1.y + bf2f(h[6]) * w1.z + bf2f(h[7]) * w1.w;
  }
#pragma unroll
  for (int d = 1; d < 64; d <<= 1) s += __shfl_xor(s, d);
  if (lane == 0) out_v[row0 + row] = s + b3[0];
}

extern "C" void kernel_launch(void* const* d_in, const int* in_sizes, int n_in,
                              void* d_out, int out_size, void* d_ws, size_t ws_size,
                              hipStream_t stream)
{
  (void)in_sizes; (void)n_in; (void)out_size;
  const float* obs   = (const float*)d_in[0];
  const float* pf_w1 = (const float*)d_in[3];
  const float* pf_b1 = (const float*)d_in[4];
  const float* pf_w2 = (const float*)d_in[5];
  const float* pf_b2 = (const float*)d_in[6];
  const float* pf_w3 = (const float*)d_in[7];
  const float* pf_b3 = (const float*)d_in[8];
  const float* pc_w1 = (const float*)d_in[9];
  const float* pc_b1 = (const float*)d_in[10];
  const float* pc_w2 = (const float*)d_in[11];
  const float* pc_b2 = (const float*)d_in[12];
  const float* pc_w3 = (const float*)d_in[13];
  const float* pc_b3 = (const float*)d_in[14];
  const float* v_w1  = (const float*)d_in[15];
  const float* v_b1  = (const float*)d_in[16];
  const float* v_w2  = (const float*)d_in[17];
  const float* v_b2  = (const float*)d_in[18];
  const float* v_w3  = (const float*)d_in[19];
  const float* v_b3  = (const float*)d_in[20];

  float* out_pi = (float*)d_out;
  float* out_v  = out_pi + (size_t)M_TOTAL * 256;

  char* ws = (char*)d_ws;
  unsigned short* wPF1 = (unsigned short*)ws;
  unsigned short* wPC1 = wPF1 + 524288;
  unsigned short* wV1  = wPC1 + 524288;
  unsigned short* wPF2 = wV1  + 524288;
  unsigned short* wPC2 = wPF2 + 1048576;
  unsigned short* wV2  = wPC2 + 1048576;
  unsigned short* wPF3 = wV2  + 1048576;
  unsigned short* wPC3 = wPF3 + 131072;
  int* cntF = (int*)(wPC3 + 131072);
  int* cntC = cntF + 64;
  int* idxF = cntC + 64;
  int* idxC = idxF + 65536;
  int* meta = idxC + 65536;
  int* idxP = meta + 128;                  // up to 81920 ints
  unsigned short* xb = (unsigned short*)(idxP + 81920);

  const size_t fixed = (size_t)9961472 + 4 * (64 + 64 + 65536 + 65536 + 128 + 81920);
  int C = 1024;
  if      (ws_size >= fixed + 5120ull * 65536 + 3145728) C = 65536;
  else if (ws_size >= fixed + 5120ull * 32768 + 3145728) C = 32768;
  else if (ws_size >= fixed + 5120ull * 16384 + 3145728) C = 16384;
  else if (ws_size >= fixed + 5120ull *  8192 + 3145728) C = 8192;
  else if (ws_size >= fixed + 5120ull *  4096 + 3145728) C = 4096;
  else if (ws_size >= fixed + 5120ull *  2048 + 3145728) C = 2048;
  const int nchunk = M_TOTAL / C;
  const int Cp = C + 512;

  unsigned short* h1p = xb + (size_t)C * 512;
  unsigned short* h2p = h1p + (size_t)Cp * 1024;

  (void)hipFuncSetAttribute((const void*)gemm256,
      hipFuncAttributeMaxDynamicSharedMemorySize, 65536);

  P8 srcs;
  srcs.p[0] = pf_w1; srcs.p[1] = pc_w1; srcs.p[2] = v_w1;
  srcs.p[3] = pf_w2; srcs.p[4] = pc_w2; srcs.p[5] = v_w2;
  srcs.p[6] = pf_w3; srcs.p[7] = pc_w3;
  fused_cast<<<2048, 256, 0, stream>>>(srcs, wPF1, cntF);
  compact_kernel<<<M_TOTAL / 256, 256, 0, stream>>>(obs, cntF, cntC, idxF, idxC, C);
  build_idxP<<<nchunk * (Cp / 256), 256, 0, stream>>>(cntF, cntC, idxF, idxC, idxP, meta, C, Cp);

  const dim3 gv(4, C / 256);
  const dim3 gp(4, Cp / 256);
  for (int c = 0; c < nchunk; ++c) {
    int row0 = c * C;
    prep_x<<<C * 512 / 256, 256, 0, stream>>>(obs, xb, row0);
    // value MLP (all rows, identity)
    gemm256<<<gv, 512, 65536, stream>>>(xb, 512, wV1, wV1, v_b1, v_b1,
                                        h1p, 1024, 512, nullptr, nullptr, C);
    gemm256<<<gv, 512, 65536, stream>>>(h1p, 1024, wV2, wV2, v_b2, v_b2,
                                        h2p, 1024, 1024, nullptr, nullptr, C);
    l3_value<<<C / 4, 256, 0, stream>>>(h2p, v_w3, v_b3, out_v, row0, C);
    // policy MLP (padded permutation: free tiles then con tiles)
    gemm256<<<gp, 512, 65536, stream>>>(xb, 512, wPF1, wPC1, pf_b1, pc_b1,
                                        h1p, 1024, 512, idxP + (size_t)c * Cp, meta + 2 * c, 0);
    gemm256<<<gp, 512, 65536, stream>>>(h1p, 1024, wPF2, wPC2, pf_b2, pc_b2,
                                        h2p, 1024, 1024, nullptr, meta + 2 * c, 0);
    l3_policy_p<<<Cp / 128, 256, 0, stream>>>(h2p, wPF3, wPC3, pf_b3, pc_b3,
                                              idxP + (size_t)c * Cp, meta + 2 * c, out_pi, row0);
  }
}

// Round 11
// 701.060 us; speedup vs baseline: 7.0069x; 1.4558x over previous
//
#include <hip/hip_runtime.h>
#include <stdint.h>

#define M_TOTAL 65536
#define IN_DIM 512
#define OBS_DIM 515

typedef __bf16 bf16x8 __attribute__((ext_vector_type(8)));
typedef float f32x4 __attribute__((ext_vector_type(4)));
typedef unsigned short u16x8 __attribute__((ext_vector_type(8)));

__device__ __forceinline__ unsigned short f2bf(float f) {
  unsigned u = __float_as_uint(f);
  u = (u + 0x7FFFu + ((u >> 16) & 1u)) >> 16;  // RNE
  return (unsigned short)u;
}
__device__ __forceinline__ float bf2f(unsigned short h) {
  return __uint_as_float(((unsigned)h) << 16);
}
__device__ __forceinline__ float fast_tanh(float z) {
  float e = __expf(2.0f * z);
  return 1.0f - 2.0f / (e + 1.0f);
}
__device__ __forceinline__ void gl16(const void* g, void* l) {
  __builtin_amdgcn_global_load_lds(
      (__attribute__((address_space(1))) void*)g,
      (__attribute__((address_space(3))) void*)l, 16, 0, 0);
}

// ---------------- fused weight cast (+ counter zeroing) ----------------
struct P8 { const float* p[8]; };

__global__ __launch_bounds__(256) void fused_cast(
    P8 srcs, unsigned short* __restrict__ dst, int* __restrict__ cnt) {
  if (blockIdx.x == 0 && threadIdx.x < 128) cnt[threadIdx.x] = 0;
  const int b0 = 524288, b1 = 1048576, b2 = 1572864, b3 = 2621440,
            b4 = 3670016, b5 = 4718592, b6 = 4849664, b7 = 4980736;
  int stride = gridDim.x * 256;
  for (int i = blockIdx.x * 256 + threadIdx.x; i < b7; i += stride) {
    const float* s; int off;
    if (i < b2)      { if (i < b0) { s = srcs.p[0]; off = i; }
                       else if (i < b1) { s = srcs.p[1]; off = i - b0; }
                       else { s = srcs.p[2]; off = i - b1; } }
    else if (i < b5) { if (i < b3) { s = srcs.p[3]; off = i - b2; }
                       else if (i < b4) { s = srcs.p[4]; off = i - b3; }
                       else { s = srcs.p[5]; off = i - b4; } }
    else             { if (i < b6) { s = srcs.p[6]; off = i - b5; }
                       else { s = srcs.p[7]; off = i - b6; } }
    dst[i] = f2bf(s[off]);
  }
}

// ---------------- compaction: hierarchical ----------------
__global__ __launch_bounds__(256) void compact_kernel(
    const float* __restrict__ obs,
    int* __restrict__ cntF, int* __restrict__ cntC,
    int* __restrict__ idxF, int* __restrict__ idxC, int C) {
  __shared__ int lcF, lcC, baseF, baseC;
  const int tid = threadIdx.x;
  const int r = blockIdx.x * 256 + tid;
  const float* g = obs + (size_t)r * OBS_DIM + IN_DIM;
  bool m = (fabsf(g[0]) <= 0.1f) && (fabsf(g[1]) <= 0.1f) && (fabsf(g[2]) <= 0.1f);
  if (tid == 0) { lcF = 0; lcC = 0; }
  __syncthreads();
  int slot = m ? atomicAdd(&lcF, 1) : atomicAdd(&lcC, 1);
  __syncthreads();
  const int c = r / C;
  if (tid == 0) {
    baseF = atomicAdd(&cntF[c], lcF);
    baseC = atomicAdd(&cntC[c], lcC);
  }
  __syncthreads();
  const int local = r - c * C;
  if (m) idxF[(size_t)c * C + baseF + slot] = local;
  else   idxC[(size_t)c * C + baseC + slot] = local;
}

// ---------------- padded permutation list (256-aligned groups) ----------------
__global__ __launch_bounds__(256) void build_idxP(
    const int* __restrict__ cntF, const int* __restrict__ cntC,
    const int* __restrict__ idxF, const int* __restrict__ idxC,
    int* __restrict__ idxP, int* __restrict__ meta, int C, int Cp) {
  const int bpc = Cp >> 8;
  const int c = blockIdx.x / bpc;
  const int i = (blockIdx.x % bpc) * 256 + threadIdx.x;
  const int cf = cntF[c], cc = cntC[c];
  const int padF = (cf + 255) & ~255;
  const int total = padF + ((cc + 255) & ~255);
  if ((blockIdx.x % bpc) == 0 && threadIdx.x == 0) {
    meta[2 * c] = padF; meta[2 * c + 1] = total;
  }
  if (i >= total) return;
  int v;
  if (i < padF) v = idxF[(size_t)c * C + (i < cf ? i : 0)];
  else { int j = i - padF; v = idxC[(size_t)c * C + (j < cc ? j : 0)]; }
  idxP[(size_t)c * Cp + i] = v;
}

__global__ __launch_bounds__(256) void prep_x(
    const float* __restrict__ obs, unsigned short* __restrict__ x, int row0) {
  int g = blockIdx.x * 256 + threadIdx.x;
  int row = g >> 9, col = g & 511;
  x[g] = f2bf(obs[(size_t)(row0 + row) * OBS_DIM + col]);
}

// ---------------- 256x256 pipelined GEMM: C = tanh(A @ B^T + bias) -------------
// ROUND-7 PROVEN CONFIG (best verified: 194 us @ K=1024, 676 TF, 0 conflicts).
// 512 threads (8 waves 2Mx4N), BK=64, double-buffered LDS (2 x 64 KiB), A AND B
// both staged via global_load_lds (keeps the vmcnt FIFO homogeneous -- mixing
// plain B register loads into the counter forces pipeline drains, rounds 8-10).
// 4 phases/K-tile, ONE barrier/phase; frag reads issued one phase ahead
// (compiler emits counted lgkmcnt); vmcnt(4) at q2/q3, never 0 mid-loop.
// __launch_bounds__(512,2): (512,4) spills the 128-reg accumulator (round 8).
#define STAGE_A(h, tt, db) { \
    const unsigned short* _s = pA[h] + (size_t)(tt) * 64 + grp8; \
    char* _d = smem + (db) * 65536 + (h) * 16384 + wbase; \
    gl16(_s, _d); gl16(_s + 32, _d + 8192); }
#define STAGE_B(h, tt, db) { \
    const unsigned short* _s = pB[h] + (size_t)(tt) * 64 + grp8; \
    char* _d = smem + (db) * 65536 + 32768 + (h) * 16384 + wbase; \
    gl16(_s, _d); gl16(_s + 32, _d + 8192); }
#define RD_A(dst, base) \
  _Pragma("unroll") for (int _f = 0; _f < 4; ++_f) \
  _Pragma("unroll") for (int _k = 0; _k < 2; ++_k) \
    dst[_f][_k] = *(const bf16x8*)((base) + _k * 8192 + a_off[_f]);
#define RD_B(dst, base) \
  _Pragma("unroll") for (int _g = 0; _g < 2; ++_g) \
  _Pragma("unroll") for (int _k = 0; _k < 2; ++_k) \
    dst[_g][_k] = *(const bf16x8*)((base) + _k * 8192 + b_off[_g]);
#define MFMA16(AF, BFR, MB, NB) \
  _Pragma("unroll") for (int _f = 0; _f < 4; ++_f) \
  _Pragma("unroll") for (int _g = 0; _g < 2; ++_g) \
  _Pragma("unroll") for (int _k = 0; _k < 2; ++_k) \
    acc[(MB) + _f][(NB) + _g] = __builtin_amdgcn_mfma_f32_16x16x32_bf16( \
        AF[_f][_k], BFR[_g][_k], acc[(MB) + _f][(NB) + _g], 0, 0, 0);
#define PH_TAIL() \
  asm volatile("" ::: "memory"); \
  __builtin_amdgcn_s_barrier(); \
  __builtin_amdgcn_sched_barrier(0);

__global__ __launch_bounds__(512, 2) void gemm256(
    const unsigned short* __restrict__ A, int lda,
    const unsigned short* __restrict__ BF, const unsigned short* __restrict__ BC,
    const float* __restrict__ biasF, const float* __restrict__ biasC,
    unsigned short* __restrict__ Cmat, int ldc, int K,
    const int* __restrict__ idxP, const int* __restrict__ meta, int Mrows)
{
  extern __shared__ char smem[];
  const int tid = threadIdx.x;

  // XCD-aware bijective swizzle (m204)
  const int nwg = gridDim.x * gridDim.y;
  const int orig = blockIdx.y * gridDim.x + blockIdx.x;
  const int qq = nwg >> 3, rr = nwg & 7, xc = orig & 7, oo = orig >> 3;
  const int wg = (xc < rr ? xc * (qq + 1) : rr * (qq + 1) + (xc - rr) * qq) + oo;
  const int n0 = (wg % gridDim.x) << 8;
  const int m0 = (wg / gridDim.x) << 8;

  const int padF  = meta ? meta[0] : (1 << 30);
  const int total = meta ? meta[1] : Mrows;
  if (m0 >= total) return;
  const unsigned short* B = (m0 < padF) ? BF : BC;
  const float* bias = (m0 < padF) ? biasF : biasC;

  const int lane = tid & 63;
  const int wv = tid >> 6;
  const int wm = wv >> 2, wn = wv & 3;
  const int lr = lane & 15;
  const int lk = lane >> 4;

  const int srow = tid >> 2;
  const int grp8 = (((tid & 3) ^ ((srow >> 1) & 3)) << 3);
  const int wbase = (tid & ~63) << 4;
  const unsigned short* pA[2];
  const unsigned short* pB[2];
#pragma unroll
  for (int h = 0; h < 2; ++h) {
    int gr = m0 + h * 128 + srow;
    int ga = idxP ? idxP[gr] : gr;
    pA[h] = A + (size_t)ga * lda;
    pB[h] = B + (size_t)(n0 + h * 128 + srow) * K;
  }

  int a_off[4], b_off[2];
#pragma unroll
  for (int f = 0; f < 4; ++f) {
    int hr = wm * 64 + f * 16 + lr;
    a_off[f] = hr * 64 + ((lk ^ ((hr >> 1) & 3)) << 4);
  }
#pragma unroll
  for (int g = 0; g < 2; ++g) {
    int hb = wn * 32 + g * 16 + lr;
    b_off[g] = hb * 64 + ((lk ^ ((hb >> 1) & 3)) << 4);
  }

  const f32x4 zero = {0.f, 0.f, 0.f, 0.f};
  f32x4 acc[8][4];
#pragma unroll
  for (int i = 0; i < 8; ++i)
#pragma unroll
    for (int j = 0; j < 4; ++j) acc[i][j] = zero;

  const int NT = K >> 6;

  // prologue: tile0 full + tile1 A0,B0 staged; preload tile0 A0/B0 frags
  STAGE_A(0, 0, 0); STAGE_B(0, 0, 0); STAGE_A(1, 0, 0); STAGE_B(1, 0, 0);
  STAGE_A(0, 1, 1); STAGE_B(0, 1, 1);
  asm volatile("s_waitcnt vmcnt(4)" ::: "memory");
  __builtin_amdgcn_s_barrier();
  asm volatile("" ::: "memory");

  bf16x8 aA[4][2], aB[4][2], b0[2][2], rb1[2][2];
  RD_A(aA, smem);            // A0 tile0
  RD_B(b0, smem + 32768);    // B0 tile0

  for (int T = 0; T < NT; ++T) {
    const int b = T & 1;
    char* bufc = smem + (b << 16);
    char* bufn = smem + ((b ^ 1) << 16);
    const bool s1 = (T + 1 < NT);
    const bool s2 = (T + 2 < NT);

    // ---- q0: MFMA A0xB0; read B1(T); stage A1(T+1)->bufn
    RD_B(rb1, bufc + 49152);
    if (s1) { STAGE_A(1, T + 1, b ^ 1); }
    __builtin_amdgcn_sched_barrier(0);
    __builtin_amdgcn_s_setprio(1);
    MFMA16(aA, b0, 0, 0);
    __builtin_amdgcn_s_setprio(0);
    PH_TAIL();

    // ---- q1: MFMA A0xB1; read A1(T); stage B1(T+1)->bufn
    RD_A(aB, bufc + 16384);
    if (s1) { STAGE_B(1, T + 1, b ^ 1); }
    __builtin_amdgcn_sched_barrier(0);
    __builtin_amdgcn_s_setprio(1);
    MFMA16(aA, rb1, 0, 2);
    __builtin_amdgcn_s_setprio(0);
    PH_TAIL();

    // ---- q2: MFMA A1xB0; stage A0(T+2)->bufc; vmcnt publishes A0/B0(T+1)
    if (s2) { STAGE_A(0, T + 2, b); }
    __builtin_amdgcn_sched_barrier(0);
    __builtin_amdgcn_s_setprio(1);
    MFMA16(aB, b0, 4, 0);
    __builtin_amdgcn_s_setprio(0);
    if (s2) asm volatile("s_waitcnt vmcnt(4)" ::: "memory");
    else    asm volatile("s_waitcnt vmcnt(0)" ::: "memory");
    PH_TAIL();

    // ---- q3: MFMA A1xB1; read A0/B0(T+1) from bufn; stage B0(T+2)->bufc;
    //          vmcnt publishes A1/B1(T+1)
    if (s1) { RD_A(aA, bufn); RD_B(b0, bufn + 32768); }
    if (s2) { STAGE_B(0, T + 2, b); }
    __builtin_amdgcn_sched_barrier(0);
    __builtin_amdgcn_s_setprio(1);
    MFMA16(aB, rb1, 4, 2);
    __builtin_amdgcn_s_setprio(0);
    if (s2) asm volatile("s_waitcnt vmcnt(4)" ::: "memory");
    else    asm volatile("s_waitcnt vmcnt(0)" ::: "memory");
    PH_TAIL();
  }

  // epilogue: bias + tanh + bf16 store
#pragma unroll
  for (int N = 0; N < 4; ++N) {
    const int nh = N >> 1, g = N & 1;
    int col = n0 + nh * 128 + wn * 32 + g * 16 + lr;
    float bv = bias[col];
#pragma unroll
    for (int M = 0; M < 8; ++M) {
      const int mh = M >> 2, f = M & 3;
      int rowb = m0 + mh * 128 + wm * 64 + f * 16 + lk * 4;
#pragma unroll
      for (int r = 0; r < 4; ++r)
        Cmat[(size_t)(rowb + r) * ldc + col] = f2bf(fast_tanh(acc[M][N][r] + bv));
    }
  }
}

// ---------------- layer3 policy ----------------
__global__ __launch_bounds__(256) void l3_policy_p(
    const unsigned short* __restrict__ H2,
    const unsigned short* __restrict__ W3F, const unsigned short* __restrict__ W3C,
    const float* __restrict__ b3F, const float* __restrict__ b3C,
    const int* __restrict__ idxP, const int* __restrict__ meta,
    float* __restrict__ out_pi, int row0)
{
  __shared__ alignas(16) unsigned short sA[128 * 32];
  __shared__ alignas(16) unsigned short sB[128 * 32];
  __shared__ int s_idx[128];
  const int tid = threadIdx.x;
  const int m0 = blockIdx.x << 7;
  const int padF = meta[0], total = meta[1];
  if (m0 >= total) return;
  const bool freeg = (m0 < padF);
  const unsigned short* W3 = freeg ? W3F : W3C;
  const float* b3 = freeg ? b3F : b3C;
  const int half = freeg ? 0 : 128;
  if (tid < 128) s_idx[tid] = idxP[m0 + tid];
  __syncthreads();

  const int lane = tid & 63;
  const int wv = tid >> 6;
  const int lr = lane & 15;
  const int lk = lane >> 4;

  const int ar0 = tid >> 2, ar1 = (256 + tid) >> 2;
  const int acol = (tid & 3) << 3;
  const unsigned short* Ap0 = H2 + (size_t)(m0 + ar0) * 1024 + acol;
  const unsigned short* Ap1 = H2 + (size_t)(m0 + ar1) * 1024 + acol;
  const unsigned short* Bp0 = W3 + (size_t)ar0 * 1024 + acol;
  const unsigned short* Bp1 = W3 + (size_t)ar1 * 1024 + acol;
  const int du = (tid & ~63) << 3;

  const f32x4 zero = {0.f, 0.f, 0.f, 0.f};
  f32x4 acc[2][8];
#pragma unroll
  for (int i = 0; i < 2; ++i)
#pragma unroll
    for (int j = 0; j < 8; ++j) acc[i][j] = zero;

  for (int kt = 0; kt < 1024; kt += 32) {
    __syncthreads();
    gl16(Ap0 + kt, &sA[du]);
    gl16(Bp0 + kt, &sB[du]);
    gl16(Ap1 + kt, &sA[du + 2048]);
    gl16(Bp1 + kt, &sB[du + 2048]);
    __syncthreads();
    bf16x8 af[2], bfr[8];
#pragma unroll
    for (int i = 0; i < 2; ++i)
      af[i] = *(const bf16x8*)&sA[((wv << 5) + (i << 4) + lr) * 32 + (lk << 3)];
#pragma unroll
    for (int j = 0; j < 8; ++j)
      bfr[j] = *(const bf16x8*)&sB[((j << 4) + lr) * 32 + (lk << 3)];
#pragma unroll
    for (int i = 0; i < 2; ++i)
#pragma unroll
      for (int j = 0; j < 8; ++j)
        acc[i][j] = __builtin_amdgcn_mfma_f32_16x16x32_bf16(af[i], bfr[j], acc[i][j], 0, 0, 0);
  }

  float bv[8];
#pragma unroll
  for (int j = 0; j < 8; ++j) bv[j] = b3[(j << 4) + lr];

#pragma unroll
  for (int i = 0; i < 2; ++i) {
#pragma unroll
    for (int r = 0; r < 4; ++r) {
      float lg[8];
      float mx = -3.4e38f;
#pragma unroll
      for (int j = 0; j < 8; ++j) { lg[j] = acc[i][j][r] + bv[j]; mx = fmaxf(mx, lg[j]); }
#pragma unroll
      for (int d = 1; d < 16; d <<= 1) mx = fmaxf(mx, __shfl_xor(mx, d));
      float s = 0.f;
#pragma unroll
      for (int j = 0; j < 8; ++j) { lg[j] = __expf(lg[j] - mx); s += lg[j]; }
#pragma unroll
      for (int d = 1; d < 16; d <<= 1) s += __shfl_xor(s, d);
      float inv = 1.f / s;
      int compact = m0 + (wv << 5) + (i << 4) + (lk << 2) + r;
      int grow = row0 + s_idx[compact - m0];
      size_t base = (size_t)grow * 256;
#pragma unroll
      for (int j = 0; j < 8; ++j)
        out_pi[base + half + (j << 4) + lr] = lg[j] * inv;
#pragma unroll
      for (int j = 0; j < 8; ++j)
        out_pi[base + (half ^ 128) + (j << 4) + lr] = 0.0f;
    }
  }
}

// ---------------- layer3 value ----------------
__global__ __launch_bounds__(256) void l3_value(
    const unsigned short* __restrict__ H2,
    const float* __restrict__ w3,
    const float* __restrict__ b3,
    float* __restrict__ out_v, int row0, int C)
{
  const int lane = threadIdx.x & 63;
  const int row = (blockIdx.x << 2) + (threadIdx.x >> 6);
  if (row >= C) return;
  float s = 0.f;
#pragma unroll
  for (int it = 0; it < 2; ++it) {
    int k = (it << 9) + (lane << 3);
    u16x8 h = *(const u16x8*)(H2 + (size_t)row * 1024 + k);
    const float4* wp = (const float4*)(w3 + k);
    float4 w0 = wp[0], w1 = wp[1];
    s += bf2f(h[0]) * w0.x + bf2f(h[1]) * w0.y + bf2f(h[2]) * w0.z + bf2f(h[3]) * w0.w;
    s += bf2f(h[4]) * w1.x + bf2f(h[5]) * w1.y + bf2f(h[6]) * w1.z + bf2f(h[7]) * w1.w;
  }
#pragma unroll
  for (int d = 1; d < 64; d <<= 1) s += __shfl_xor(s, d);
  if (lane == 0) out_v[row0 + row] = s + b3[0];
}

extern "C" void kernel_launch(void* const* d_in, const int* in_sizes, int n_in,
                              void* d_out, int out_size, void* d_ws, size_t ws_size,
                              hipStream_t stream)
{
  (void)in_sizes; (void)n_in; (void)out_size;
  const float* obs   = (const float*)d_in[0];
  const float* pf_w1 = (const float*)d_in[3];
  const float* pf_b1 = (const float*)d_in[4];
  const float* pf_w2 = (const float*)d_in[5];
  const float* pf_b2 = (const float*)d_in[6];
  const float* pf_w3 = (const float*)d_in[7];
  const float* pf_b3 = (const float*)d_in[8];
  const float* pc_w1 = (const float*)d_in[9];
  const float* pc_b1 = (const float*)d_in[10];
  const float* pc_w2 = (const float*)d_in[11];
  const float* pc_b2 = (const float*)d_in[12];
  const float* pc_w3 = (const float*)d_in[13];
  const float* pc_b3 = (const float*)d_in[14];
  const float* v_w1  = (const float*)d_in[15];
  const float* v_b1  = (const float*)d_in[16];
  const float* v_w2  = (const float*)d_in[17];
  const float* v_b2  = (const float*)d_in[18];
  const float* v_w3  = (const float*)d_in[19];
  const float* v_b3  = (const float*)d_in[20];

  float* out_pi = (float*)d_out;
  float* out_v  = out_pi + (size_t)M_TOTAL * 256;

  char* ws = (char*)d_ws;
  unsigned short* wPF1 = (unsigned short*)ws;
  unsigned short* wPC1 = wPF1 + 524288;
  unsigned short* wV1  = wPC1 + 524288;
  unsigned short* wPF2 = wV1  + 524288;
  unsigned short* wPC2 = wPF2 + 1048576;
  unsigned short* wV2  = wPC2 + 1048576;
  unsigned short* wPF3 = wV2  + 1048576;
  unsigned short* wPC3 = wPF3 + 131072;
  int* cntF = (int*)(wPC3 + 131072);
  int* cntC = cntF + 64;
  int* idxF = cntC + 64;
  int* idxC = idxF + 65536;
  int* meta = idxC + 65536;
  int* idxP = meta + 128;                  // up to 81920 ints
  unsigned short* xb = (unsigned short*)(idxP + 81920);

  const size_t fixed = (size_t)9961472 + 4 * (64 + 64 + 65536 + 65536 + 128 + 81920);
  int C = 1024;
  if      (ws_size >= fixed + 5120ull * 65536 + 3145728) C = 65536;
  else if (ws_size >= fixed + 5120ull * 32768 + 3145728) C = 32768;
  else if (ws_size >= fixed + 5120ull * 16384 + 3145728) C = 16384;
  else if (ws_size >= fixed + 5120ull *  8192 + 3145728) C = 8192;
  else if (ws_size >= fixed + 5120ull *  4096 + 3145728) C = 4096;
  else if (ws_size >= fixed + 5120ull *  2048 + 3145728) C = 2048;
  const int nchunk = M_TOTAL / C;
  const int Cp = C + 512;

  unsigned short* h1p = xb + (size_t)C * 512;
  unsigned short* h2p = h1p + (size_t)Cp * 1024;

  (void)hipFuncSetAttribute((const void*)gemm256,
      hipFuncAttributeMaxDynamicSharedMemorySize, 131072);

  P8 srcs;
  srcs.p[0] = pf_w1; srcs.p[1] = pc_w1; srcs.p[2] = v_w1;
  srcs.p[3] = pf_w2; srcs.p[4] = pc_w2; srcs.p[5] = v_w2;
  srcs.p[6] = pf_w3; srcs.p[7] = pc_w3;
  fused_cast<<<2048, 256, 0, stream>>>(srcs, wPF1, cntF);
  compact_kernel<<<M_TOTAL / 256, 256, 0, stream>>>(obs, cntF, cntC, idxF, idxC, C);
  build_idxP<<<nchunk * (Cp / 256), 256, 0, stream>>>(cntF, cntC, idxF, idxC, idxP, meta, C, Cp);

  const dim3 gv(4, C / 256);
  const dim3 gp(4, Cp / 256);
  for (int c = 0; c < nchunk; ++c) {
    int row0 = c * C;
    prep_x<<<C * 512 / 256, 256, 0, stream>>>(obs, xb, row0);
    // value MLP (all rows, identity)
    gemm256<<<gv, 512, 131072, stream>>>(xb, 512, wV1, wV1, v_b1, v_b1,
                                         h1p, 1024, 512, nullptr, nullptr, C);
    gemm256<<<gv, 512, 131072, stream>>>(h1p, 1024, wV2, wV2, v_b2, v_b2,
                                         h2p, 1024, 1024, nullptr, nullptr, C);
    l3_value<<<C / 4, 256, 0, stream>>>(h2p, v_w3, v_b3, out_v, row0, C);
    // policy MLP (padded permutation: free tiles then con tiles)
    gemm256<<<gp, 512, 131072, stream>>>(xb, 512, wPF1, wPC1, pf_b1, pc_b1,
                                         h1p, 1024, 512, idxP + (size_t)c * Cp, meta + 2 * c, 0);
    gemm256<<<gp, 512, 131072, stream>>>(h1p, 1024, wPF2, wPC2, pf_b2, pc_b2,
                                         h2p, 1024, 1024, nullptr, meta + 2 * c, 0);
    l3_policy_p<<<Cp / 128, 256, 0, stream>>>(h2p, wPF3, wPC3, pf_b3, pc_b3,
                                              idxP + (size_t)c * Cp, meta + 2 * c, out_pi, row0);
  }
}

// Round 12
// 682.474 us; speedup vs baseline: 7.1977x; 1.0272x over previous
//
#include <hip/hip_runtime.h>
#include <stdint.h>

#define M_TOTAL 65536
#define IN_DIM 512
#define OBS_DIM 515

typedef __bf16 bf16x8 __attribute__((ext_vector_type(8)));
typedef float f32x4 __attribute__((ext_vector_type(4)));
typedef unsigned short u16x8 __attribute__((ext_vector_type(8)));

__device__ __forceinline__ unsigned short f2bf(float f) {
  unsigned u = __float_as_uint(f);
  u = (u + 0x7FFFu + ((u >> 16) & 1u)) >> 16;  // RNE
  return (unsigned short)u;
}
__device__ __forceinline__ float bf2f(unsigned short h) {
  return __uint_as_float(((unsigned)h) << 16);
}
__device__ __forceinline__ float fast_tanh(float z) {
  float e = __expf(2.0f * z);
  return 1.0f - 2.0f / (e + 1.0f);
}
__device__ __forceinline__ void gl16(const void* g, void* l) {
  __builtin_amdgcn_global_load_lds(
      (__attribute__((address_space(1))) void*)g,
      (__attribute__((address_space(3))) void*)l, 16, 0, 0);
}

// ---------------- fused weight cast (+ counter zeroing) ----------------
struct P8 { const float* p[8]; };

__global__ __launch_bounds__(256) void fused_cast(
    P8 srcs, unsigned short* __restrict__ dst, int* __restrict__ cnt) {
  if (blockIdx.x == 0 && threadIdx.x < 128) cnt[threadIdx.x] = 0;
  const int b0 = 524288, b1 = 1048576, b2 = 1572864, b3 = 2621440,
            b4 = 3670016, b5 = 4718592, b6 = 4849664, b7 = 4980736;
  int stride = gridDim.x * 256;
  for (int i = blockIdx.x * 256 + threadIdx.x; i < b7; i += stride) {
    const float* s; int off;
    if (i < b2)      { if (i < b0) { s = srcs.p[0]; off = i; }
                       else if (i < b1) { s = srcs.p[1]; off = i - b0; }
                       else { s = srcs.p[2]; off = i - b1; } }
    else if (i < b5) { if (i < b3) { s = srcs.p[3]; off = i - b2; }
                       else if (i < b4) { s = srcs.p[4]; off = i - b3; }
                       else { s = srcs.p[5]; off = i - b4; } }
    else             { if (i < b6) { s = srcs.p[6]; off = i - b5; }
                       else { s = srcs.p[7]; off = i - b6; } }
    dst[i] = f2bf(s[off]);
  }
}

// ---------------- compaction: hierarchical ----------------
__global__ __launch_bounds__(256) void compact_kernel(
    const float* __restrict__ obs,
    int* __restrict__ cntF, int* __restrict__ cntC,
    int* __restrict__ idxF, int* __restrict__ idxC, int C) {
  __shared__ int lcF, lcC, baseF, baseC;
  const int tid = threadIdx.x;
  const int r = blockIdx.x * 256 + tid;
  const float* g = obs + (size_t)r * OBS_DIM + IN_DIM;
  bool m = (fabsf(g[0]) <= 0.1f) && (fabsf(g[1]) <= 0.1f) && (fabsf(g[2]) <= 0.1f);
  if (tid == 0) { lcF = 0; lcC = 0; }
  __syncthreads();
  int slot = m ? atomicAdd(&lcF, 1) : atomicAdd(&lcC, 1);
  __syncthreads();
  const int c = r / C;
  if (tid == 0) {
    baseF = atomicAdd(&cntF[c], lcF);
    baseC = atomicAdd(&cntC[c], lcC);
  }
  __syncthreads();
  const int local = r - c * C;
  if (m) idxF[(size_t)c * C + baseF + slot] = local;
  else   idxC[(size_t)c * C + baseC + slot] = local;
}

// ---------------- padded permutation list (256-aligned groups) ----------------
__global__ __launch_bounds__(256) void build_idxP(
    const int* __restrict__ cntF, const int* __restrict__ cntC,
    const int* __restrict__ idxF, const int* __restrict__ idxC,
    int* __restrict__ idxP, int* __restrict__ meta, int C, int Cp) {
  const int bpc = Cp >> 8;
  const int c = blockIdx.x / bpc;
  const int i = (blockIdx.x % bpc) * 256 + threadIdx.x;
  const int cf = cntF[c], cc = cntC[c];
  const int padF = (cf + 255) & ~255;
  const int total = padF + ((cc + 255) & ~255);
  if ((blockIdx.x % bpc) == 0 && threadIdx.x == 0) {
    meta[2 * c] = padF; meta[2 * c + 1] = total;
  }
  if (i >= total) return;
  int v;
  if (i < padF) v = idxF[(size_t)c * C + (i < cf ? i : 0)];
  else { int j = i - padF; v = idxC[(size_t)c * C + (j < cc ? j : 0)]; }
  idxP[(size_t)c * Cp + i] = v;
}

// prep_x also pre-initializes out_v[row] = v_b3 (bias) for the fused v-dot.
__global__ __launch_bounds__(256) void prep_x(
    const float* __restrict__ obs, unsigned short* __restrict__ x, int row0,
    const float* __restrict__ vb3, float* __restrict__ outv) {
  int g = blockIdx.x * 256 + threadIdx.x;
  int row = g >> 9, col = g & 511;
  x[g] = f2bf(obs[(size_t)(row0 + row) * OBS_DIM + col]);
  if (col == 0) outv[row] = vb3[0];
}

// ---------------- 256x256 pipelined GEMM: C = tanh(A @ B^T + bias) -------------
// ROUND-7 PROVEN CONFIG (194 us @ K=1024, 676 TF, 0 conflicts). Main loop frozen.
// 512 threads (8 waves 2Mx4N), BK=64, double-buffered LDS (2 x 64 KiB), A AND B
// both staged via global_load_lds (keeps the vmcnt FIFO homogeneous -- mixing
// plain B register loads into the counter forces pipeline drains, rounds 8-10).
// 4 phases/K-tile, ONE barrier/phase; frag reads issued one phase ahead
// (compiler emits counted lgkmcnt); vmcnt(4) at q2/q3, never 0 mid-loop.
// __launch_bounds__(512,2): (512,4) spills the 128-reg accumulator (round 8).
// NEW (round 12): optional fused value-head epilogue -- if vw3 != null, skip the
// C store and atomicAdd per-row partial dots sum(tanh(acc+bias)*w3[col]) into
// outv (out_v pre-initialized to b3 by prep_x). Epilogue-only change.
#define STAGE_A(h, tt, db) { \
    const unsigned short* _s = pA[h] + (size_t)(tt) * 64 + grp8; \
    char* _d = smem + (db) * 65536 + (h) * 16384 + wbase; \
    gl16(_s, _d); gl16(_s + 32, _d + 8192); }
#define STAGE_B(h, tt, db) { \
    const unsigned short* _s = pB[h] + (size_t)(tt) * 64 + grp8; \
    char* _d = smem + (db) * 65536 + 32768 + (h) * 16384 + wbase; \
    gl16(_s, _d); gl16(_s + 32, _d + 8192); }
#define RD_A(dst, base) \
  _Pragma("unroll") for (int _f = 0; _f < 4; ++_f) \
  _Pragma("unroll") for (int _k = 0; _k < 2; ++_k) \
    dst[_f][_k] = *(const bf16x8*)((base) + _k * 8192 + a_off[_f]);
#define RD_B(dst, base) \
  _Pragma("unroll") for (int _g = 0; _g < 2; ++_g) \
  _Pragma("unroll") for (int _k = 0; _k < 2; ++_k) \
    dst[_g][_k] = *(const bf16x8*)((base) + _k * 8192 + b_off[_g]);
#define MFMA16(AF, BFR, MB, NB) \
  _Pragma("unroll") for (int _f = 0; _f < 4; ++_f) \
  _Pragma("unroll") for (int _g = 0; _g < 2; ++_g) \
  _Pragma("unroll") for (int _k = 0; _k < 2; ++_k) \
    acc[(MB) + _f][(NB) + _g] = __builtin_amdgcn_mfma_f32_16x16x32_bf16( \
        AF[_f][_k], BFR[_g][_k], acc[(MB) + _f][(NB) + _g], 0, 0, 0);
#define PH_TAIL() \
  asm volatile("" ::: "memory"); \
  __builtin_amdgcn_s_barrier(); \
  __builtin_amdgcn_sched_barrier(0);

__global__ __launch_bounds__(512, 2) void gemm256(
    const unsigned short* __restrict__ A, int lda,
    const unsigned short* __restrict__ BF, const unsigned short* __restrict__ BC,
    const float* __restrict__ biasF, const float* __restrict__ biasC,
    unsigned short* __restrict__ Cmat, int ldc, int K,
    const int* __restrict__ idxP, const int* __restrict__ meta, int Mrows,
    const float* __restrict__ vw3, float* __restrict__ outv)
{
  extern __shared__ char smem[];
  const int tid = threadIdx.x;

  // XCD-aware bijective swizzle (m204)
  const int nwg = gridDim.x * gridDim.y;
  const int orig = blockIdx.y * gridDim.x + blockIdx.x;
  const int qq = nwg >> 3, rr = nwg & 7, xc = orig & 7, oo = orig >> 3;
  const int wg = (xc < rr ? xc * (qq + 1) : rr * (qq + 1) + (xc - rr) * qq) + oo;
  const int n0 = (wg % gridDim.x) << 8;
  const int m0 = (wg / gridDim.x) << 8;

  const int padF  = meta ? meta[0] : (1 << 30);
  const int total = meta ? meta[1] : Mrows;
  if (m0 >= total) return;
  const unsigned short* B = (m0 < padF) ? BF : BC;
  const float* bias = (m0 < padF) ? biasF : biasC;

  const int lane = tid & 63;
  const int wv = tid >> 6;
  const int wm = wv >> 2, wn = wv & 3;
  const int lr = lane & 15;
  const int lk = lane >> 4;

  const int srow = tid >> 2;
  const int grp8 = (((tid & 3) ^ ((srow >> 1) & 3)) << 3);
  const int wbase = (tid & ~63) << 4;
  const unsigned short* pA[2];
  const unsigned short* pB[2];
#pragma unroll
  for (int h = 0; h < 2; ++h) {
    int gr = m0 + h * 128 + srow;
    int ga = idxP ? idxP[gr] : gr;
    pA[h] = A + (size_t)ga * lda;
    pB[h] = B + (size_t)(n0 + h * 128 + srow) * K;
  }

  int a_off[4], b_off[2];
#pragma unroll
  for (int f = 0; f < 4; ++f) {
    int hr = wm * 64 + f * 16 + lr;
    a_off[f] = hr * 64 + ((lk ^ ((hr >> 1) & 3)) << 4);
  }
#pragma unroll
  for (int g = 0; g < 2; ++g) {
    int hb = wn * 32 + g * 16 + lr;
    b_off[g] = hb * 64 + ((lk ^ ((hb >> 1) & 3)) << 4);
  }

  const f32x4 zero = {0.f, 0.f, 0.f, 0.f};
  f32x4 acc[8][4];
#pragma unroll
  for (int i = 0; i < 8; ++i)
#pragma unroll
    for (int j = 0; j < 4; ++j) acc[i][j] = zero;

  const int NT = K >> 6;

  // prologue: tile0 full + tile1 A0,B0 staged; preload tile0 A0/B0 frags
  STAGE_A(0, 0, 0); STAGE_B(0, 0, 0); STAGE_A(1, 0, 0); STAGE_B(1, 0, 0);
  STAGE_A(0, 1, 1); STAGE_B(0, 1, 1);
  asm volatile("s_waitcnt vmcnt(4)" ::: "memory");
  __builtin_amdgcn_s_barrier();
  asm volatile("" ::: "memory");

  bf16x8 aA[4][2], aB[4][2], b0[2][2], rb1[2][2];
  RD_A(aA, smem);            // A0 tile0
  RD_B(b0, smem + 32768);    // B0 tile0

  for (int T = 0; T < NT; ++T) {
    const int b = T & 1;
    char* bufc = smem + (b << 16);
    char* bufn = smem + ((b ^ 1) << 16);
    const bool s1 = (T + 1 < NT);
    const bool s2 = (T + 2 < NT);

    // ---- q0: MFMA A0xB0; read B1(T); stage A1(T+1)->bufn
    RD_B(rb1, bufc + 49152);
    if (s1) { STAGE_A(1, T + 1, b ^ 1); }
    __builtin_amdgcn_sched_barrier(0);
    __builtin_amdgcn_s_setprio(1);
    MFMA16(aA, b0, 0, 0);
    __builtin_amdgcn_s_setprio(0);
    PH_TAIL();

    // ---- q1: MFMA A0xB1; read A1(T); stage B1(T+1)->bufn
    RD_A(aB, bufc + 16384);
    if (s1) { STAGE_B(1, T + 1, b ^ 1); }
    __builtin_amdgcn_sched_barrier(0);
    __builtin_amdgcn_s_setprio(1);
    MFMA16(aA, rb1, 0, 2);
    __builtin_amdgcn_s_setprio(0);
    PH_TAIL();

    // ---- q2: MFMA A1xB0; stage A0(T+2)->bufc; vmcnt publishes A0/B0(T+1)
    if (s2) { STAGE_A(0, T + 2, b); }
    __builtin_amdgcn_sched_barrier(0);
    __builtin_amdgcn_s_setprio(1);
    MFMA16(aB, b0, 4, 0);
    __builtin_amdgcn_s_setprio(0);
    if (s2) asm volatile("s_waitcnt vmcnt(4)" ::: "memory");
    else    asm volatile("s_waitcnt vmcnt(0)" ::: "memory");
    PH_TAIL();

    // ---- q3: MFMA A1xB1; read A0/B0(T+1) from bufn; stage B0(T+2)->bufc;
    //          vmcnt publishes A1/B1(T+1)
    if (s1) { RD_A(aA, bufn); RD_B(b0, bufn + 32768); }
    if (s2) { STAGE_B(0, T + 2, b); }
    __builtin_amdgcn_sched_barrier(0);
    __builtin_amdgcn_s_setprio(1);
    MFMA16(aB, rb1, 4, 2);
    __builtin_amdgcn_s_setprio(0);
    if (s2) asm volatile("s_waitcnt vmcnt(4)" ::: "memory");
    else    asm volatile("s_waitcnt vmcnt(0)" ::: "memory");
    PH_TAIL();
  }

  if (vw3) {
    // fused value head: v[row] += sum_cols tanh(acc+bias)*w3[col]
#pragma unroll
    for (int N = 0; N < 4; ++N) {
      const int nh = N >> 1, g = N & 1;
      int col = n0 + nh * 128 + wn * 32 + g * 16 + lr;
      float bv = bias[col];
      float w = vw3[col];
#pragma unroll
      for (int M = 0; M < 8; ++M)
#pragma unroll
        for (int r = 0; r < 4; ++r)
          acc[M][N][r] = fast_tanh(acc[M][N][r] + bv) * w;
    }
#pragma unroll
    for (int M = 0; M < 8; ++M)
#pragma unroll
      for (int r = 0; r < 4; ++r) {
        float s = acc[M][0][r] + acc[M][1][r] + acc[M][2][r] + acc[M][3][r];
#pragma unroll
        for (int d = 1; d < 16; d <<= 1) s += __shfl_xor(s, d);
        if (lr == 0) {
          int row = m0 + (M >> 2) * 128 + wm * 64 + (M & 3) * 16 + lk * 4 + r;
          atomicAdd(&outv[row], s);
        }
      }
    return;
  }

  // epilogue: bias + tanh + bf16 store
#pragma unroll
  for (int N = 0; N < 4; ++N) {
    const int nh = N >> 1, g = N & 1;
    int col = n0 + nh * 128 + wn * 32 + g * 16 + lr;
    float bv = bias[col];
#pragma unroll
    for (int M = 0; M < 8; ++M) {
      const int mh = M >> 2, f = M & 3;
      int rowb = m0 + mh * 128 + wm * 64 + f * 16 + lk * 4;
#pragma unroll
      for (int r = 0; r < 4; ++r)
        Cmat[(size_t)(rowb + r) * ldc + col] = f2bf(fast_tanh(acc[M][N][r] + bv));
    }
  }
}

// ---------------- layer3 policy ----------------
__global__ __launch_bounds__(256) void l3_policy_p(
    const unsigned short* __restrict__ H2,
    const unsigned short* __restrict__ W3F, const unsigned short* __restrict__ W3C,
    const float* __restrict__ b3F, const float* __restrict__ b3C,
    const int* __restrict__ idxP, const int* __restrict__ meta,
    float* __restrict__ out_pi, int row0)
{
  __shared__ alignas(16) unsigned short sA[128 * 32];
  __shared__ alignas(16) unsigned short sB[128 * 32];
  __shared__ int s_idx[128];
  const int tid = threadIdx.x;
  const int m0 = blockIdx.x << 7;
  const int padF = meta[0], total = meta[1];
  if (m0 >= total) return;
  const bool freeg = (m0 < padF);
  const unsigned short* W3 = freeg ? W3F : W3C;
  const float* b3 = freeg ? b3F : b3C;
  const int half = freeg ? 0 : 128;
  if (tid < 128) s_idx[tid] = idxP[m0 + tid];
  __syncthreads();

  const int lane = tid & 63;
  const int wv = tid >> 6;
  const int lr = lane & 15;
  const int lk = lane >> 4;

  const int ar0 = tid >> 2, ar1 = (256 + tid) >> 2;
  const int acol = (tid & 3) << 3;
  const unsigned short* Ap0 = H2 + (size_t)(m0 + ar0) * 1024 + acol;
  const unsigned short* Ap1 = H2 + (size_t)(m0 + ar1) * 1024 + acol;
  const unsigned short* Bp0 = W3 + (size_t)ar0 * 1024 + acol;
  const unsigned short* Bp1 = W3 + (size_t)ar1 * 1024 + acol;
  const int du = (tid & ~63) << 3;

  const f32x4 zero = {0.f, 0.f, 0.f, 0.f};
  f32x4 acc[2][8];
#pragma unroll
  for (int i = 0; i < 2; ++i)
#pragma unroll
    for (int j = 0; j < 8; ++j) acc[i][j] = zero;

  for (int kt = 0; kt < 1024; kt += 32) {
    __syncthreads();
    gl16(Ap0 + kt, &sA[du]);
    gl16(Bp0 + kt, &sB[du]);
    gl16(Ap1 + kt, &sA[du + 2048]);
    gl16(Bp1 + kt, &sB[du + 2048]);
    __syncthreads();
    bf16x8 af[2], bfr[8];
#pragma unroll
    for (int i = 0; i < 2; ++i)
      af[i] = *(const bf16x8*)&sA[((wv << 5) + (i << 4) + lr) * 32 + (lk << 3)];
#pragma unroll
    for (int j = 0; j < 8; ++j)
      bfr[j] = *(const bf16x8*)&sB[((j << 4) + lr) * 32 + (lk << 3)];
#pragma unroll
    for (int i = 0; i < 2; ++i)
#pragma unroll
      for (int j = 0; j < 8; ++j)
        acc[i][j] = __builtin_amdgcn_mfma_f32_16x16x32_bf16(af[i], bfr[j], acc[i][j], 0, 0, 0);
  }

  float bv[8];
#pragma unroll
  for (int j = 0; j < 8; ++j) bv[j] = b3[(j << 4) + lr];

#pragma unroll
  for (int i = 0; i < 2; ++i) {
#pragma unroll
    for (int r = 0; r < 4; ++r) {
      float lg[8];
      float mx = -3.4e38f;
#pragma unroll
      for (int j = 0; j < 8; ++j) { lg[j] = acc[i][j][r] + bv[j]; mx = fmaxf(mx, lg[j]); }
#pragma unroll
      for (int d = 1; d < 16; d <<= 1) mx = fmaxf(mx, __shfl_xor(mx, d));
      float s = 0.f;
#pragma unroll
      for (int j = 0; j < 8; ++j) { lg[j] = __expf(lg[j] - mx); s += lg[j]; }
#pragma unroll
      for (int d = 1; d < 16; d <<= 1) s += __shfl_xor(s, d);
      float inv = 1.f / s;
      int compact = m0 + (wv << 5) + (i << 4) + (lk << 2) + r;
      int grow = row0 + s_idx[compact - m0];
      size_t base = (size_t)grow * 256;
#pragma unroll
      for (int j = 0; j < 8; ++j)
        out_pi[base + half + (j << 4) + lr] = lg[j] * inv;
#pragma unroll
      for (int j = 0; j < 8; ++j)
        out_pi[base + (half ^ 128) + (j << 4) + lr] = 0.0f;
    }
  }
}

extern "C" void kernel_launch(void* const* d_in, const int* in_sizes, int n_in,
                              void* d_out, int out_size, void* d_ws, size_t ws_size,
                              hipStream_t stream)
{
  (void)in_sizes; (void)n_in; (void)out_size;
  const float* obs   = (const float*)d_in[0];
  const float* pf_w1 = (const float*)d_in[3];
  const float* pf_b1 = (const float*)d_in[4];
  const float* pf_w2 = (const float*)d_in[5];
  const float* pf_b2 = (const float*)d_in[6];
  const float* pf_w3 = (const float*)d_in[7];
  const float* pf_b3 = (const float*)d_in[8];
  const float* pc_w1 = (const float*)d_in[9];
  const float* pc_b1 = (const float*)d_in[10];
  const float* pc_w2 = (const float*)d_in[11];
  const float* pc_b2 = (const float*)d_in[12];
  const float* pc_w3 = (const float*)d_in[13];
  const float* pc_b3 = (const float*)d_in[14];
  const float* v_w1  = (const float*)d_in[15];
  const float* v_b1  = (const float*)d_in[16];
  const float* v_w2  = (const float*)d_in[17];
  const float* v_b2  = (const float*)d_in[18];
  const float* v_w3  = (const float*)d_in[19];
  const float* v_b3  = (const float*)d_in[20];

  float* out_pi = (float*)d_out;
  float* out_v  = out_pi + (size_t)M_TOTAL * 256;

  char* ws = (char*)d_ws;
  unsigned short* wPF1 = (unsigned short*)ws;
  unsigned short* wPC1 = wPF1 + 524288;
  unsigned short* wV1  = wPC1 + 524288;
  unsigned short* wPF2 = wV1  + 524288;
  unsigned short* wPC2 = wPF2 + 1048576;
  unsigned short* wV2  = wPC2 + 1048576;
  unsigned short* wPF3 = wV2  + 1048576;
  unsigned short* wPC3 = wPF3 + 131072;
  int* cntF = (int*)(wPC3 + 131072);
  int* cntC = cntF + 64;
  int* idxF = cntC + 64;
  int* idxC = idxF + 65536;
  int* meta = idxC + 65536;
  int* idxP = meta + 128;                  // up to 81920 ints
  unsigned short* xb = (unsigned short*)(idxP + 81920);

  const size_t fixed = (size_t)9961472 + 4 * (64 + 64 + 65536 + 65536 + 128 + 81920);
  int C = 1024;
  if      (ws_size >= fixed + 5120ull * 65536 + 3145728) C = 65536;
  else if (ws_size >= fixed + 5120ull * 32768 + 3145728) C = 32768;
  else if (ws_size >= fixed + 5120ull * 16384 + 3145728) C = 16384;
  else if (ws_size >= fixed + 5120ull *  8192 + 3145728) C = 8192;
  else if (ws_size >= fixed + 5120ull *  4096 + 3145728) C = 4096;
  else if (ws_size >= fixed + 5120ull *  2048 + 3145728) C = 2048;
  const int nchunk = M_TOTAL / C;
  const int Cp = C + 512;

  unsigned short* h1p = xb + (size_t)C * 512;
  unsigned short* h2p = h1p + (size_t)Cp * 1024;

  (void)hipFuncSetAttribute((const void*)gemm256,
      hipFuncAttributeMaxDynamicSharedMemorySize, 131072);

  P8 srcs;
  srcs.p[0] = pf_w1; srcs.p[1] = pc_w1; srcs.p[2] = v_w1;
  srcs.p[3] = pf_w2; srcs.p[4] = pc_w2; srcs.p[5] = v_w2;
  srcs.p[6] = pf_w3; srcs.p[7] = pc_w3;
  fused_cast<<<2048, 256, 0, stream>>>(srcs, wPF1, cntF);
  compact_kernel<<<M_TOTAL / 256, 256, 0, stream>>>(obs, cntF, cntC, idxF, idxC, C);
  build_idxP<<<nchunk * (Cp / 256), 256, 0, stream>>>(cntF, cntC, idxF, idxC, idxP, meta, C, Cp);

  const dim3 gv(4, C / 256);
  const dim3 gp(4, Cp / 256);
  for (int c = 0; c < nchunk; ++c) {
    int row0 = c * C;
    // prep: cast x chunk + init out_v to v bias
    prep_x<<<C * 512 / 256, 256, 0, stream>>>(obs, xb, row0, v_b3, out_v + row0);
    // value MLP (all rows, identity); L2 fuses the v-dot epilogue (atomicAdd)
    gemm256<<<gv, 512, 131072, stream>>>(xb, 512, wV1, wV1, v_b1, v_b1,
                                         h1p, 1024, 512, nullptr, nullptr, C,
                                         nullptr, nullptr);
    gemm256<<<gv, 512, 131072, stream>>>(h1p, 1024, wV2, wV2, v_b2, v_b2,
                                         h2p, 1024, 1024, nullptr, nullptr, C,
                                         v_w3, out_v + row0);
    // policy MLP (padded permutation: free tiles then con tiles)
    gemm256<<<gp, 512, 131072, stream>>>(xb, 512, wPF1, wPC1, pf_b1, pc_b1,
                                         h1p, 1024, 512, idxP + (size_t)c * Cp, meta + 2 * c, 0,
                                         nullptr, nullptr);
    gemm256<<<gp, 512, 131072, stream>>>(h1p, 1024, wPF2, wPC2, pf_b2, pc_b2,
                                         h2p, 1024, 1024, nullptr, meta + 2 * c, 0,
                                         nullptr, nullptr);
    l3_policy_p<<<Cp / 128, 256, 0, stream>>>(h2p, wPF3, wPC3, pf_b3, pc_b3,
                                              idxP + (size_t)c * Cp, meta + 2 * c, out_pi, row0);
  }
}